// Round 2
// baseline (5456.872 us; speedup 1.0000x reference)
//
#include <hip/hip_runtime.h>

typedef unsigned long long ull;

#define N0_ 100000
#define N1_ 50000
#define N2_ 25000
#define N3_ 12500
#define EDG 1600000
#define CAP1 600000
#define CAP2 200000
#define CAP3 80000

#define HALF_BYTES 51200000ULL   // N0_*128*4 = half of a big fp64 buffer

struct Sel { ull prefix; int remaining; };

// ---------------- kernels ----------------

__global__ void sentinel_k(float* o, float v) { if (threadIdx.x == 0) o[0] = v; }

// C[n,128] = A[n,128] @ W[128,128], fp64 accumulate. 64 rows/block, 256 thr.
template <typename TA, typename TC>
__global__ __launch_bounds__(256) void matmul128(const TA* __restrict__ A,
    const float* __restrict__ W, TC* __restrict__ C, int n) {
  __shared__ double Al[64 * 33];
  __shared__ double Wl[32 * 128];
  int tid = threadIdx.x;
  int colb = tid & 31;        // cols colb, colb+32, colb+64, colb+96
  int rg = tid >> 5;          // 0..7 -> rows rg*8..rg*8+7
  int row0 = blockIdx.x * 64;
  double acc[8][4];
#pragma unroll
  for (int r = 0; r < 8; ++r)
#pragma unroll
    for (int j = 0; j < 4; ++j) acc[r][j] = 0.0;
  for (int kt = 0; kt < 128; kt += 32) {
    for (int i = tid; i < 64 * 32; i += 256) {
      int r = i >> 5, kk = i & 31;
      int row = row0 + r;
      Al[r * 33 + kk] = (row < n) ? (double)A[(size_t)row * 128 + kt + kk] : 0.0;
    }
    for (int i = tid; i < 32 * 128; i += 256) {
      int kk = i >> 7, c = i & 127;
      Wl[i] = (double)W[(size_t)(kt + kk) * 128 + c];
    }
    __syncthreads();
#pragma unroll 4
    for (int kk = 0; kk < 32; ++kk) {
      double b0 = Wl[kk * 128 + colb];
      double b1 = Wl[kk * 128 + colb + 32];
      double b2 = Wl[kk * 128 + colb + 64];
      double b3 = Wl[kk * 128 + colb + 96];
#pragma unroll
      for (int r = 0; r < 8; ++r) {
        double a = Al[(rg * 8 + r) * 33 + kk];
        acc[r][0] += a * b0; acc[r][1] += a * b1;
        acc[r][2] += a * b2; acc[r][3] += a * b3;
      }
    }
    __syncthreads();
  }
  for (int r = 0; r < 8; ++r) {
    int row = row0 + rg * 8 + r;
    if (row < n) {
      size_t o = (size_t)row * 128 + colb;
      C[o] = (TC)acc[r][0]; C[o + 32] = (TC)acc[r][1];
      C[o + 64] = (TC)acc[r][2]; C[o + 96] = (TC)acc[r][3];
    }
  }
}

// y[i,c] = sum_{p} h[src_p,c]*dinv[src_p]*dinv[i] + h[i,c]/deg[i] + b[c]
template <typename TH, typename TY, bool RELU>
__global__ __launch_bounds__(256) void agg_conv(const TH* __restrict__ h,
    const int* __restrict__ off, const int* __restrict__ csrc,
    const double* __restrict__ dinv, const double* __restrict__ dgi,
    const float* __restrict__ bias, TY* __restrict__ y, int n) {
  int c = threadIdx.x & 127;
  int node = blockIdx.x * 2 + (threadIdx.x >> 7);
  if (node >= n) return;
  double di = dinv[node];
  double acc = (double)h[(size_t)node * 128 + c] * dgi[node];
  int p1 = off[node + 1];
  for (int p = off[node]; p < p1; ++p) {
    int s = csrc[p];
    acc += (double)h[(size_t)s * 128 + c] * (dinv[s] * di);
  }
  double r = acc + (double)bias[c];
  if (RELU) r = r > 0.0 ? r : 0.0;
  y[(size_t)node * 128 + c] = (TY)r;
}

__global__ void count_deg(const int* __restrict__ dst, const int* mptr, int mstat,
                          int* __restrict__ cnt) {
  int m = mptr ? ((*mptr < mstat) ? *mptr : mstat) : mstat;
  int e = blockIdx.x * 256 + threadIdx.x;
  if (e < m) atomicAdd(&cnt[dst[e]], 1);
}

__global__ void fin_deg(const int* __restrict__ cnt, double* __restrict__ dinv,
                        double* __restrict__ dgi, int n) {
  int i = blockIdx.x * 256 + threadIdx.x;
  if (i < n) {
    double d = 1.0 + (double)cnt[i];
    dinv[i] = 1.0 / sqrt(d);
    dgi[i] = 1.0 / d;
  }
}

__global__ __launch_bounds__(1024) void scan_excl(const int* __restrict__ in,
                                                  int* __restrict__ out, int n) {
  __shared__ int ls[1024];
  int t = threadIdx.x;
  int chunk = (n + 1023) >> 10;
  int base = t * chunk;
  int s = 0;
  for (int j = 0; j < chunk; ++j) { int i = base + j; if (i < n) s += in[i]; }
  ls[t] = s; __syncthreads();
  for (int d = 1; d < 1024; d <<= 1) {
    int v = (t >= d) ? ls[t - d] : 0;
    __syncthreads();
    ls[t] += v;
    __syncthreads();
  }
  int run = ls[t] - s;
  for (int j = 0; j < chunk; ++j) {
    int i = base + j;
    if (i < n) { out[i] = run; run += in[i]; }
  }
  if (t == 1023) out[n] = ls[1023];
}

__global__ void csr_fill(const int* __restrict__ src, const int* __restrict__ dst,
                         const int* mptr, int mstat, const int* __restrict__ off,
                         int* __restrict__ cursor, int* __restrict__ csrs) {
  int m = mptr ? ((*mptr < mstat) ? *mptr : mstat) : mstat;
  int e = blockIdx.x * 256 + threadIdx.x;
  if (e < m) {
    int d = dst[e];
    int pos = off[d] + atomicAdd(&cursor[d], 1);
    csrs[pos] = src[e];
  }
}

template <typename T>
__global__ __launch_bounds__(256) void bn_stats(const T* __restrict__ x, int n,
                                                double* __restrict__ sums) {
  __shared__ double lsum[256], lsq[256];
  int c = threadIdx.x & 127, half = threadIdx.x >> 7;
  double s = 0, q = 0;
  for (int row = blockIdx.x * 2 + half; row < n; row += gridDim.x * 2) {
    double v = (double)x[(size_t)row * 128 + c];
    s += v; q += v * v;
  }
  lsum[threadIdx.x] = s; lsq[threadIdx.x] = q;
  __syncthreads();
  if (half == 0) {
    s = lsum[c] + lsum[c + 128];
    q = lsq[c] + lsq[c + 128];
    atomicAdd(&sums[c], s);
    atomicAdd(&sums[128 + c], q);
  }
}

__global__ void bn_final(const double* __restrict__ sums, const float* __restrict__ g,
                         const float* __restrict__ beta, double invn,
                         double* __restrict__ ss) {
  int c = threadIdx.x;
  double m = sums[c] * invn;
  double v = sums[128 + c] * invn - m * m;
  double sc = (double)g[c] / sqrt(v + 1e-5);
  ss[c] = sc;
  ss[128 + c] = (double)beta[c] - m * sc;
}

template <typename T>
__global__ void bn_apply_relu(T* __restrict__ x, const double* __restrict__ ss, size_t total) {
  size_t i = (size_t)blockIdx.x * 256 + threadIdx.x;
  if (i < total) {
    int c = (int)(i & 127);
    double v = (double)x[i] * ss[c] + ss[128 + c];
    x[i] = (T)(v > 0.0 ? v : 0.0);
  }
}

__global__ void wnorm_k(const float* __restrict__ w, double* __restrict__ wn) {
  __shared__ double red[128];
  int c = threadIdx.x;
  double v = (double)w[c];
  red[c] = v * v;
  __syncthreads();
  for (int s = 64; s > 0; s >>= 1) { if (c < s) red[c] += red[c + s]; __syncthreads(); }
  if (c == 0) wn[0] = sqrt(red[0]);
}

__global__ __launch_bounds__(256) void score_key_k(const double* __restrict__ x,
    const float* __restrict__ w, const double* __restrict__ wn,
    ull* __restrict__ keys, int n) {
  __shared__ double red[256];
  int c = threadIdx.x & 127;
  int node = blockIdx.x * 2 + (threadIdx.x >> 7);
  double p = 0.0;
  if (node < n) p = x[(size_t)node * 128 + c] * (double)w[c];
  red[threadIdx.x] = p;
  __syncthreads();
  for (int s = 64; s > 0; s >>= 1) {
    if (c < s) red[threadIdx.x] += red[threadIdx.x + s];
    __syncthreads();
  }
  if (c == 0 && node < n) {
    double sc = tanh(red[threadIdx.x] / wn[0]);
    ull u = (ull)__double_as_longlong(sc);
    u = (u >> 63) ? ~u : (u | 0x8000000000000000ULL);
    keys[node] = u;
  }
}

__global__ void sel_init(Sel* sel, int k) {
  if (threadIdx.x == 0) { sel->prefix = 0ULL; sel->remaining = k; }
}

__global__ void rs_hist(const ull* __restrict__ keys, int n, const Sel* __restrict__ sel,
                        int shift, int pass, int* __restrict__ hist) {
  __shared__ int lh[256];
  lh[threadIdx.x] = 0;
  __syncthreads();
  int i = blockIdx.x * 256 + threadIdx.x;
  if (i < n) {
    ull k = keys[i];
    bool ok = (pass == 0) || (((k ^ sel->prefix) >> (shift + 8)) == 0);
    if (ok) atomicAdd(&lh[(int)((k >> shift) & 255)], 1);
  }
  __syncthreads();
  if (lh[threadIdx.x]) atomicAdd(&hist[threadIdx.x], lh[threadIdx.x]);
}

__global__ void rs_pick(const int* __restrict__ hist, Sel* sel, int shift) {
  __shared__ int lh[256];
  lh[threadIdx.x] = hist[threadIdx.x];
  __syncthreads();
  if (threadIdx.x == 0) {
    int rem = sel->remaining;
    for (int b = 255; b >= 0; --b) {
      int c = lh[b];
      if (c >= rem) { sel->prefix |= ((ull)b) << shift; break; }
      rem -= c;
    }
    sel->remaining = rem;
  }
}

__global__ void eq_flags(const ull* __restrict__ keys, const Sel* __restrict__ sel,
                         int* __restrict__ eqf, int n) {
  int i = blockIdx.x * 256 + threadIdx.x;
  if (i < n) eqf[i] = (keys[i] == sel->prefix) ? 1 : 0;
}

__global__ void kept_flags(const ull* __restrict__ keys, const Sel* __restrict__ sel,
                           const int* __restrict__ eqpre, int* __restrict__ kept, int n) {
  int i = blockIdx.x * 256 + threadIdx.x;
  if (i < n) {
    ull u = keys[i], p = sel->prefix;
    kept[i] = (u > p || (u == p && eqpre[i] < sel->remaining)) ? 1 : 0;
  }
}

__global__ void build_idx(const int* __restrict__ kept, const int* __restrict__ npre,
                          int* __restrict__ newid, int* __restrict__ idx, int n) {
  int i = blockIdx.x * 256 + threadIdx.x;
  if (i < n && kept[i]) {
    int nid = npre[i];
    newid[i] = nid;
    idx[nid] = i;
  }
}

__global__ void downcast_k(const double* __restrict__ x, float* __restrict__ y, int total) {
  int i = blockIdx.x * 256 + threadIdx.x;
  if (i < total) y[i] = (float)x[i];
}

__global__ void gather_rows(const double* __restrict__ xs, const int* __restrict__ idx,
                            double* __restrict__ xo, int k) {
  int i = blockIdx.x * 256 + threadIdx.x;
  if (i < k * 128) xo[i] = xs[(size_t)idx[i >> 7] * 128 + (i & 127)];
}

__global__ void edge_compact(const int* __restrict__ src, const int* __restrict__ dst,
                             const int* mptr, int mstat, const int* __restrict__ kept,
                             const int* __restrict__ newid, int* __restrict__ nsrc,
                             int* __restrict__ ndst, int* __restrict__ mN, int cap) {
  int m = mptr ? ((*mptr < mstat) ? *mptr : mstat) : mstat;
  int e = blockIdx.x * 256 + threadIdx.x;
  if (e < m) {
    int s = src[e], d = dst[e];
    if (kept[s] && kept[d]) {
      int pos = atomicAdd(mN, 1);
      if (pos < cap) { nsrc[pos] = newid[s]; ndst[pos] = newid[d]; }
    }
  }
}

__global__ void scatter_add_rows(float* __restrict__ h, const float* __restrict__ t,
                                 const int* __restrict__ idx, int k) {
  int i = blockIdx.x * 256 + threadIdx.x;
  if (i < k * 128) h[(size_t)idx[i >> 7] * 128 + (i & 127)] += t[i];
}

// ---------------- host ----------------

extern "C" void kernel_launch(void* const* d_in, const int* in_sizes, int n_in,
                              void* d_out, int out_size, void* d_ws, size_t ws_size,
                              hipStream_t stream) {
  (void)in_sizes; (void)out_size;
  if (n_in < 17) return;
  const float* x_in   = (const float*)d_in[0];
  const int*   ei     = (const int*)  d_in[1];
  const float* in_W   = (const float*)d_in[2];
  const float* in_b   = (const float*)d_in[3];
  const float* dn_W   = (const float*)d_in[4];
  const float* dn_b   = (const float*)d_in[5];
  const float* dn_g   = (const float*)d_in[6];
  const float* dn_bt  = (const float*)d_in[7];
  const float* pool_w = (const float*)d_in[8];
  const float* bot_W  = (const float*)d_in[9];
  const float* bot_b  = (const float*)d_in[10];
  const float* up_W   = (const float*)d_in[11];
  const float* up_b   = (const float*)d_in[12];
  const float* up_g   = (const float*)d_in[13];
  const float* up_bt  = (const float*)d_in[14];
  const float* out_W  = (const float*)d_in[15];
  const float* out_b  = (const float*)d_in[16];
  float* outp = (float*)d_out;

  char* base = (char*)d_ws;
  size_t off = 0;
  auto alloc = [&](size_t b) -> void* {
    void* r = base + off;
    off = (off + b + 255) & ~(size_t)255;
    return r;
  };
  // Two big fp64 ping-pong buffers (102.4 MB each); xs snapshots alias their
  // dead regions per the liveness schedule below.
  double* bufA = (double*)alloc((size_t)N0_ * 128 * 8);
  double* bufB = (double*)alloc((size_t)N0_ * 128 * 8);
  float* xs0f = (float*)((char*)bufB + HALF_BYTES);   // 51.2 MB  (B upper half)
  float* xs1f = (float*)((char*)bufA + HALF_BYTES);   // 25.6 MB  (A[51.2,76.8))
  float* xs2f = (float*)((char*)bufA + HALF_BYTES + 25600000ULL); // 12.8 MB (A[76.8,89.6))

  int* src1 = (int*)alloc((size_t)CAP1 * 4); int* dst1 = (int*)alloc((size_t)CAP1 * 4);
  int* src2 = (int*)alloc((size_t)CAP2 * 4); int* dst2 = (int*)alloc((size_t)CAP2 * 4);
  int* src3 = (int*)alloc((size_t)CAP3 * 4); int* dst3 = (int*)alloc((size_t)CAP3 * 4);
  int* csrs0 = (int*)alloc((size_t)EDG * 4);
  int* csrs1 = (int*)alloc((size_t)CAP1 * 4);
  int* csrs2 = (int*)alloc((size_t)CAP2 * 4);
  int* csrs3 = (int*)alloc((size_t)CAP3 * 4);
  int* csro0 = (int*)alloc((size_t)(N0_ + 1) * 4);
  int* csro1 = (int*)alloc((size_t)(N1_ + 1) * 4);
  int* csro2 = (int*)alloc((size_t)(N2_ + 1) * 4);
  int* csro3 = (int*)alloc((size_t)(N3_ + 1) * 4);
  double* dinv0 = (double*)alloc((size_t)N0_ * 8); double* dgi0 = (double*)alloc((size_t)N0_ * 8);
  double* dinv1 = (double*)alloc((size_t)N1_ * 8); double* dgi1 = (double*)alloc((size_t)N1_ * 8);
  double* dinv2 = (double*)alloc((size_t)N2_ * 8); double* dgi2 = (double*)alloc((size_t)N2_ * 8);
  double* dinv3 = (double*)alloc((size_t)N3_ * 8); double* dgi3 = (double*)alloc((size_t)N3_ * 8);
  ull* keys = (ull*)alloc((size_t)N0_ * 8);
  int* eqf   = (int*)alloc((size_t)N0_ * 4);
  int* eqpre = (int*)alloc((size_t)(N0_ + 1) * 4);
  int* kept  = (int*)alloc((size_t)N0_ * 4);
  int* npre  = (int*)alloc((size_t)(N0_ + 1) * 4);
  int* newid = (int*)alloc((size_t)N0_ * 4);
  int* degcnt = (int*)alloc((size_t)N0_ * 4);
  int* cursor = (int*)alloc((size_t)N0_ * 4);
  int* idx0 = (int*)alloc((size_t)N1_ * 4);
  int* idx1 = (int*)alloc((size_t)N2_ * 4);
  int* idx2 = (int*)alloc((size_t)N3_ * 4);
  int* hist = (int*)alloc(256 * 4);
  Sel* sel  = (Sel*)alloc(256);
  int* mcnt = (int*)alloc(256);
  double* bns = (double*)alloc(256 * 8);
  double* ssb = (double*)alloc(256 * 8);
  double* wn  = (double*)alloc(256);
  if (off > ws_size) {  // signal: absmax will be ~ws_size
    sentinel_k<<<1, 64, 0, stream>>>(outp, (float)ws_size);
    return;
  }

  const int nL[4]   = {N0_, N1_, N2_, N3_};
  const int capL[4] = {EDG, CAP1, CAP2, CAP3};
  const int* srcL[4] = {ei, src1, src2, src3};
  const int* dstL[4] = {ei + EDG, dst1, dst2, dst3};
  int* wsrcL[4] = {nullptr, src1, src2, src3};
  int* wdstL[4] = {nullptr, dst1, dst2, dst3};
  int* csrsL[4] = {csrs0, csrs1, csrs2, csrs3};
  int* csroL[4] = {csro0, csro1, csro2, csro3};
  double* dinvL[4] = {dinv0, dinv1, dinv2, dinv3};
  double* dgiL[4]  = {dgi0, dgi1, dgi2, dgi3};
  int* mptrL[4] = {nullptr, mcnt, mcnt + 1, mcnt + 2};
  int* idxL[3] = {idx0, idx1, idx2};

  auto cdiv = [](int a, int b) { return (a + b - 1) / b; };

  auto build_csr = [&](int L) {
    hipMemsetAsync(degcnt, 0, (size_t)nL[L] * 4, stream);
    count_deg<<<cdiv(capL[L], 256), 256, 0, stream>>>(dstL[L], mptrL[L], capL[L], degcnt);
    fin_deg<<<cdiv(nL[L], 256), 256, 0, stream>>>(degcnt, dinvL[L], dgiL[L], nL[L]);
    scan_excl<<<1, 1024, 0, stream>>>(degcnt, csroL[L], nL[L]);
    hipMemsetAsync(cursor, 0, (size_t)nL[L] * 4, stream);
    csr_fill<<<cdiv(capL[L], 256), 256, 0, stream>>>(srcL[L], dstL[L], mptrL[L], capL[L],
                                                     csroL[L], cursor, csrsL[L]);
  };

  auto bn_d = [&](double* xp, int n, const float* g, const float* b) {
    hipMemsetAsync(bns, 0, 2048, stream);
    bn_stats<double><<<256, 256, 0, stream>>>(xp, n, bns);
    bn_final<<<1, 128, 0, stream>>>(bns, g, b, 1.0 / (double)n, ssb);
    bn_apply_relu<double><<<cdiv(n * 128, 256), 256, 0, stream>>>(xp, ssb, (size_t)n * 128);
  };
  auto bn_f = [&](float* xp, int n, const float* g, const float* b) {
    hipMemsetAsync(bns, 0, 2048, stream);
    bn_stats<float><<<256, 256, 0, stream>>>(xp, n, bns);
    bn_final<<<1, 128, 0, stream>>>(bns, g, b, 1.0 / (double)n, ssb);
    bn_apply_relu<float><<<cdiv(n * 128, 256), 256, 0, stream>>>(xp, ssb, (size_t)n * 128);
  };

  // pool level i: xcur (n_i x128 fp64) -> keys/top-k; snapshot to xsf (fp32);
  // gather kept rows (fp64) into xnext; compact edges; build level i+1 CSR.
  auto pool = [&](int i, const double* xcur, float* xsf, double* xnext) {
    int n = nL[i], k = nL[i + 1];
    wnorm_k<<<1, 128, 0, stream>>>(pool_w + i * 128, wn);
    score_key_k<<<cdiv(n, 2), 256, 0, stream>>>(xcur, pool_w + i * 128, wn, keys, n);
    sel_init<<<1, 64, 0, stream>>>(sel, k);
    for (int p = 0; p < 8; ++p) {
      int shift = 56 - 8 * p;
      hipMemsetAsync(hist, 0, 1024, stream);
      rs_hist<<<cdiv(n, 256), 256, 0, stream>>>(keys, n, sel, shift, p, hist);
      rs_pick<<<1, 256, 0, stream>>>(hist, sel, shift);
    }
    eq_flags<<<cdiv(n, 256), 256, 0, stream>>>(keys, sel, eqf, n);
    scan_excl<<<1, 1024, 0, stream>>>(eqf, eqpre, n);
    kept_flags<<<cdiv(n, 256), 256, 0, stream>>>(keys, sel, eqpre, kept, n);
    scan_excl<<<1, 1024, 0, stream>>>(kept, npre, n);
    build_idx<<<cdiv(n, 256), 256, 0, stream>>>(kept, npre, newid, idxL[i], n);
    downcast_k<<<cdiv(n * 128, 256), 256, 0, stream>>>(xcur, xsf, n * 128);
    gather_rows<<<cdiv(k * 128, 256), 256, 0, stream>>>(xcur, idxL[i], xnext, k);
    hipMemsetAsync(mptrL[i + 1], 0, 4, stream);
    edge_compact<<<cdiv(capL[i], 256), 256, 0, stream>>>(srcL[i], dstL[i], mptrL[i], capL[i],
        kept, newid, wsrcL[i + 1], wdstL[i + 1], mptrL[i + 1], capL[i + 1]);
    build_csr(i + 1);
  };

  // ---- level 0 CSR + initial conv:  x0 -> bufA, h in bufB ----
  build_csr(0);
  matmul128<float, double><<<cdiv(N0_, 64), 256, 0, stream>>>(x_in, in_W, bufB, N0_);
  agg_conv<double, double, false><<<cdiv(N0_, 2), 256, 0, stream>>>(
      bufB, csro0, csrs0, dinv0, dgi0, in_b, bufA, N0_);

  // ---- down level 0: x in A, h in B, y back to A; xs0f -> B upper; x1 -> B lower ----
  matmul128<double, double><<<cdiv(N0_, 64), 256, 0, stream>>>(bufA, dn_W, bufB, N0_);
  agg_conv<double, double, false><<<cdiv(N0_, 2), 256, 0, stream>>>(
      bufB, csro0, csrs0, dinv0, dgi0, dn_b, bufA, N0_);
  bn_d(bufA, N0_, dn_g, dn_bt);
  pool(0, bufA, xs0f, bufB);

  // ---- down level 1: x in B lower, h in A lower, y back to B; xs1f -> A+51.2M; x2 -> A lower ----
  matmul128<double, double><<<cdiv(N1_, 64), 256, 0, stream>>>(bufB, dn_W + 16384, bufA, N1_);
  agg_conv<double, double, false><<<cdiv(N1_, 2), 256, 0, stream>>>(
      bufA, csro1, csrs1, dinv1, dgi1, dn_b + 128, bufB, N1_);
  bn_d(bufB, N1_, dn_g + 128, dn_bt + 128);
  pool(1, bufB, xs1f, bufA);

  // ---- down level 2: x in A lower, h in B lower, y back to A; xs2f -> A+76.8M; x3 -> B lower ----
  matmul128<double, double><<<cdiv(N2_, 64), 256, 0, stream>>>(bufA, dn_W + 32768, bufB, N2_);
  agg_conv<double, double, false><<<cdiv(N2_, 2), 256, 0, stream>>>(
      bufB, csro2, csrs2, dinv2, dgi2, dn_b + 256, bufA, N2_);
  bn_d(bufA, N2_, dn_g + 256, dn_bt + 256);
  pool(2, bufA, xs2f, bufB);

  // ---- bottom: x3 in B lower, h3 -> A lower, z3 (fp32, relu) -> B lower ----
  matmul128<double, double><<<cdiv(N3_, 64), 256, 0, stream>>>(bufB, bot_W, bufA, N3_);
  float* zf = (float*)bufB;
  float* hf = (float*)bufA;
  float* tf = outp;  // d_out as scratch until final write (fully overwritten at end)
  agg_conv<double, float, true><<<cdiv(N3_, 2), 256, 0, stream>>>(
      bufA, csro3, csrs3, dinv3, dgi3, bot_b, zf, N3_);

  // ---- up path (fp32): z in B lower, hf in A lower ----
  for (int u = 0; u < 3; ++u) {
    int l = 2 - u;
    int nl = nL[l], nz = nL[l + 1];
    const float* Wt = up_W + u * 32768;          // rows [0:128)  -> unpooled part
    const float* Wb = up_W + u * 32768 + 16384;  // rows [128:256)-> skip part
    const float* xsf = (u == 0) ? xs2f : (u == 1) ? xs1f : xs0f;
    matmul128<float, float><<<cdiv(nz, 64), 256, 0, stream>>>(zf, Wt, tf, nz);
    matmul128<float, float><<<cdiv(nl, 64), 256, 0, stream>>>(xsf, Wb, hf, nl);
    scatter_add_rows<<<cdiv(nz * 128, 256), 256, 0, stream>>>(hf, tf, idxL[l], nz);
    agg_conv<float, float, false><<<cdiv(nl, 2), 256, 0, stream>>>(
        hf, csroL[l], csrsL[l], dinvL[l], dgiL[l], up_b + u * 128, zf, nl);
    bn_f(zf, nl, up_g + u * 128, up_bt + u * 128);
  }

  // ---- final conv -> d_out ----
  matmul128<float, float><<<cdiv(N0_, 64), 256, 0, stream>>>(zf, out_W, hf, N0_);
  agg_conv<float, float, false><<<cdiv(N0_, 2), 256, 0, stream>>>(
      hf, csro0, csrs0, dinv0, dgi0, out_b, outp, N0_);
}

// Round 3
// 4745.871 us; speedup vs baseline: 1.1498x; 1.1498x over previous
//
#include <hip/hip_runtime.h>

typedef unsigned long long ull;

#define N0_ 100000
#define N1_ 50000
#define N2_ 25000
#define N3_ 12500
#define EDG 1600000
#define CAP1 600000
#define CAP2 200000
#define CAP3 80000

#define HALF_BYTES 51200000ULL   // N0_*128*4 = half of a big fp64 buffer

struct Sel { ull prefix; int remaining; };

// ---------------- kernels ----------------

__global__ void sentinel_k(float* o, float v) { if (threadIdx.x == 0) o[0] = v; }

// C[n,128] = A[n,128] @ W[128,128] (+bias), fp64 accumulate. 64 rows/block.
template <typename TA, typename TC>
__global__ __launch_bounds__(256) void matmul128(const TA* __restrict__ A,
    const float* __restrict__ W, const float* __restrict__ bias,
    TC* __restrict__ C, int n) {
  __shared__ double Al[64 * 33];
  __shared__ double Wl[32 * 128];
  int tid = threadIdx.x;
  int colb = tid & 31;        // cols colb, colb+32, colb+64, colb+96
  int rg = tid >> 5;          // 0..7 -> rows rg*8..rg*8+7
  int row0 = blockIdx.x * 64;
  double acc[8][4];
#pragma unroll
  for (int r = 0; r < 8; ++r)
#pragma unroll
    for (int j = 0; j < 4; ++j) acc[r][j] = 0.0;
  for (int kt = 0; kt < 128; kt += 32) {
    for (int i = tid; i < 64 * 32; i += 256) {
      int r = i >> 5, kk = i & 31;
      int row = row0 + r;
      Al[r * 33 + kk] = (row < n) ? (double)A[(size_t)row * 128 + kt + kk] : 0.0;
    }
    for (int i = tid; i < 32 * 128; i += 256) {
      int kk = i >> 7, c = i & 127;
      Wl[i] = (double)W[(size_t)(kt + kk) * 128 + c];
    }
    __syncthreads();
#pragma unroll 4
    for (int kk = 0; kk < 32; ++kk) {
      double b0 = Wl[kk * 128 + colb];
      double b1 = Wl[kk * 128 + colb + 32];
      double b2 = Wl[kk * 128 + colb + 64];
      double b3 = Wl[kk * 128 + colb + 96];
#pragma unroll
      for (int r = 0; r < 8; ++r) {
        double a = Al[(rg * 8 + r) * 33 + kk];
        acc[r][0] += a * b0; acc[r][1] += a * b1;
        acc[r][2] += a * b2; acc[r][3] += a * b3;
      }
    }
    __syncthreads();
  }
  double bb0 = 0, bb1 = 0, bb2 = 0, bb3 = 0;
  if (bias) {
    bb0 = (double)bias[colb]; bb1 = (double)bias[colb + 32];
    bb2 = (double)bias[colb + 64]; bb3 = (double)bias[colb + 96];
  }
  for (int r = 0; r < 8; ++r) {
    int row = row0 + rg * 8 + r;
    if (row < n) {
      size_t o = (size_t)row * 128 + colb;
      C[o] = (TC)(acc[r][0] + bb0); C[o + 32] = (TC)(acc[r][1] + bb1);
      C[o + 64] = (TC)(acc[r][2] + bb2); C[o + 96] = (TC)(acc[r][3] + bb3);
    }
  }
}

// y[i,c] = di * sum_p h[src_p,c]*csrw[p] + h[i,c]*dgi[i] + b[c]
// unroll-8 neighbor loop: 8 independent row-gathers in flight per wave.
template <typename TH, typename TY, bool RELU>
__global__ __launch_bounds__(256) void agg_conv(const TH* __restrict__ h,
    const int* __restrict__ off, const int* __restrict__ csrc,
    const double* __restrict__ csrw,
    const double* __restrict__ dinv, const double* __restrict__ dgi,
    const float* __restrict__ bias, TY* __restrict__ y, int n) {
  int c = threadIdx.x & 127;
  int node = blockIdx.x * 2 + (threadIdx.x >> 7);
  if (node >= n) return;
  double di = dinv[node];
  double self = (double)h[(size_t)node * 128 + c] * dgi[node];
  double accA = 0.0, accB = 0.0;
  int p = off[node], p1 = off[node + 1];
  for (; p + 8 <= p1; p += 8) {
    int s0 = csrc[p + 0], s1 = csrc[p + 1], s2 = csrc[p + 2], s3 = csrc[p + 3];
    int s4 = csrc[p + 4], s5 = csrc[p + 5], s6 = csrc[p + 6], s7 = csrc[p + 7];
    double w0 = csrw[p + 0], w1 = csrw[p + 1], w2 = csrw[p + 2], w3 = csrw[p + 3];
    double w4 = csrw[p + 4], w5 = csrw[p + 5], w6 = csrw[p + 6], w7 = csrw[p + 7];
    double v0 = (double)h[(size_t)s0 * 128 + c];
    double v1 = (double)h[(size_t)s1 * 128 + c];
    double v2 = (double)h[(size_t)s2 * 128 + c];
    double v3 = (double)h[(size_t)s3 * 128 + c];
    double v4 = (double)h[(size_t)s4 * 128 + c];
    double v5 = (double)h[(size_t)s5 * 128 + c];
    double v6 = (double)h[(size_t)s6 * 128 + c];
    double v7 = (double)h[(size_t)s7 * 128 + c];
    accA += v0 * w0; accB += v1 * w1; accA += v2 * w2; accB += v3 * w3;
    accA += v4 * w4; accB += v5 * w5; accA += v6 * w6; accB += v7 * w7;
  }
  for (; p + 4 <= p1; p += 4) {
    int s0 = csrc[p + 0], s1 = csrc[p + 1], s2 = csrc[p + 2], s3 = csrc[p + 3];
    double w0 = csrw[p + 0], w1 = csrw[p + 1], w2 = csrw[p + 2], w3 = csrw[p + 3];
    double v0 = (double)h[(size_t)s0 * 128 + c];
    double v1 = (double)h[(size_t)s1 * 128 + c];
    double v2 = (double)h[(size_t)s2 * 128 + c];
    double v3 = (double)h[(size_t)s3 * 128 + c];
    accA += v0 * w0; accB += v1 * w1; accA += v2 * w2; accB += v3 * w3;
  }
  for (; p < p1; ++p)
    accA += (double)h[(size_t)csrc[p] * 128 + c] * csrw[p];
  double r = (accA + accB) * di + self + (bias ? (double)bias[c] : 0.0);
  if (RELU) r = r > 0.0 ? r : 0.0;
  y[(size_t)node * 128 + c] = (TY)r;
}

__global__ void count_deg(const int* __restrict__ dst, const int* mptr, int mstat,
                          int* __restrict__ cnt) {
  int m = mptr ? ((*mptr < mstat) ? *mptr : mstat) : mstat;
  int e = blockIdx.x * 256 + threadIdx.x;
  if (e < m) atomicAdd(&cnt[dst[e]], 1);
}

__global__ void fin_deg(const int* __restrict__ cnt, double* __restrict__ dinv,
                        double* __restrict__ dgi, int n) {
  int i = blockIdx.x * 256 + threadIdx.x;
  if (i < n) {
    double d = 1.0 + (double)cnt[i];
    dinv[i] = 1.0 / sqrt(d);
    dgi[i] = 1.0 / d;
  }
}

__global__ __launch_bounds__(1024) void scan_excl(const int* __restrict__ in,
                                                  int* __restrict__ out, int n) {
  __shared__ int ls[1024];
  int t = threadIdx.x;
  int chunk = (n + 1023) >> 10;
  int base = t * chunk;
  int s = 0;
  for (int j = 0; j < chunk; ++j) { int i = base + j; if (i < n) s += in[i]; }
  ls[t] = s; __syncthreads();
  for (int d = 1; d < 1024; d <<= 1) {
    int v = (t >= d) ? ls[t - d] : 0;
    __syncthreads();
    ls[t] += v;
    __syncthreads();
  }
  int run = ls[t] - s;
  for (int j = 0; j < chunk; ++j) {
    int i = base + j;
    if (i < n) { out[i] = run; run += in[i]; }
  }
  if (t == 1023) out[n] = ls[1023];
}

__global__ void csr_fill(const int* __restrict__ src, const int* __restrict__ dst,
                         const int* mptr, int mstat, const int* __restrict__ off,
                         int* __restrict__ cursor, int* __restrict__ csrs,
                         double* __restrict__ csrw, const double* __restrict__ dinv) {
  int m = mptr ? ((*mptr < mstat) ? *mptr : mstat) : mstat;
  int e = blockIdx.x * 256 + threadIdx.x;
  if (e < m) {
    int d = dst[e];
    int s = src[e];
    int pos = off[d] + atomicAdd(&cursor[d], 1);
    csrs[pos] = s;
    csrw[pos] = dinv[s];
  }
}

// fixed grid of 256 blocks; deterministic per-block partials (no atomics).
template <typename T>
__global__ __launch_bounds__(256) void bn_stats(const T* __restrict__ x, int n,
                                                double* __restrict__ part) {
  __shared__ double lsum[256], lsq[256];
  int c = threadIdx.x & 127, half = threadIdx.x >> 7;
  double s = 0, q = 0;
  for (int row = blockIdx.x * 2 + half; row < n; row += 512) {
    double v = (double)x[(size_t)row * 128 + c];
    s += v; q += v * v;
  }
  lsum[threadIdx.x] = s; lsq[threadIdx.x] = q;
  __syncthreads();
  if (half == 0) {
    part[blockIdx.x * 256 + c] = lsum[c] + lsum[c + 128];
    part[blockIdx.x * 256 + 128 + c] = lsq[c] + lsq[c + 128];
  }
}

__global__ void bn_final(const double* __restrict__ part, const float* __restrict__ g,
                         const float* __restrict__ beta, double invn,
                         double* __restrict__ ss) {
  int c = threadIdx.x;  // 128
  double s = 0, q = 0;
  for (int b = 0; b < 256; ++b) {
    s += part[b * 256 + c];
    q += part[b * 256 + 128 + c];
  }
  double m = s * invn;
  double v = q * invn - m * m;
  double sc = (double)g[c] / sqrt(v + 1e-5);
  ss[c] = sc;
  ss[128 + c] = (double)beta[c] - m * sc;
}

// apply BN+ReLU in place; optionally write fp32 snapshot (skip connection).
template <typename T>
__global__ void bn_apply_relu(T* __restrict__ x, const double* __restrict__ ss,
                              float* __restrict__ snap, size_t total) {
  size_t i = (size_t)blockIdx.x * 256 + threadIdx.x;
  if (i < total) {
    int c = (int)(i & 127);
    double v = (double)x[i] * ss[c] + ss[128 + c];
    v = v > 0.0 ? v : 0.0;
    x[i] = (T)v;
    if (snap) snap[i] = (float)v;
  }
}

__global__ void wnorm_k(const float* __restrict__ w, double* __restrict__ wn) {
  __shared__ double red[128];
  int c = threadIdx.x;
  double v = (double)w[c];
  red[c] = v * v;
  __syncthreads();
  for (int s = 64; s > 0; s >>= 1) { if (c < s) red[c] += red[c + s]; __syncthreads(); }
  if (c == 0) wn[0] = sqrt(red[0]);
}

__global__ __launch_bounds__(256) void score_key_k(const double* __restrict__ x,
    const float* __restrict__ w, const double* __restrict__ wn,
    ull* __restrict__ keys, int n) {
  __shared__ double red[256];
  int c = threadIdx.x & 127;
  int node = blockIdx.x * 2 + (threadIdx.x >> 7);
  double p = 0.0;
  if (node < n) p = x[(size_t)node * 128 + c] * (double)w[c];
  red[threadIdx.x] = p;
  __syncthreads();
  for (int s = 64; s > 0; s >>= 1) {
    if (c < s) red[threadIdx.x] += red[threadIdx.x + s];
    __syncthreads();
  }
  if (c == 0 && node < n) {
    double sc = tanh(red[threadIdx.x] / wn[0]);
    ull u = (ull)__double_as_longlong(sc);
    u = (u >> 63) ? ~u : (u | 0x8000000000000000ULL);
    keys[node] = u;
  }
}

__global__ void sel_init(Sel* sel, int k) {
  if (threadIdx.x == 0) { sel->prefix = 0ULL; sel->remaining = k; }
}

__global__ void rs_hist(const ull* __restrict__ keys, int n, const Sel* __restrict__ sel,
                        int shift, int pass, int* __restrict__ hist) {
  __shared__ int lh[256];
  lh[threadIdx.x] = 0;
  __syncthreads();
  int i = blockIdx.x * 256 + threadIdx.x;
  if (i < n) {
    ull k = keys[i];
    bool ok = (pass == 0) || (((k ^ sel->prefix) >> (shift + 8)) == 0);
    if (ok) atomicAdd(&lh[(int)((k >> shift) & 255)], 1);
  }
  __syncthreads();
  if (lh[threadIdx.x]) atomicAdd(&hist[threadIdx.x], lh[threadIdx.x]);
}

__global__ void rs_pick(const int* __restrict__ hist, Sel* sel, int shift) {
  __shared__ int lh[256];
  lh[threadIdx.x] = hist[threadIdx.x];
  __syncthreads();
  if (threadIdx.x == 0) {
    int rem = sel->remaining;
    for (int b = 255; b >= 0; --b) {
      int c = lh[b];
      if (c >= rem) { sel->prefix |= ((ull)b) << shift; break; }
      rem -= c;
    }
    sel->remaining = rem;
  }
}

__global__ void eq_flags(const ull* __restrict__ keys, const Sel* __restrict__ sel,
                         int* __restrict__ eqf, int n) {
  int i = blockIdx.x * 256 + threadIdx.x;
  if (i < n) eqf[i] = (keys[i] == sel->prefix) ? 1 : 0;
}

__global__ void kept_flags(const ull* __restrict__ keys, const Sel* __restrict__ sel,
                           const int* __restrict__ eqpre, int* __restrict__ kept, int n) {
  int i = blockIdx.x * 256 + threadIdx.x;
  if (i < n) {
    ull u = keys[i], p = sel->prefix;
    kept[i] = (u > p || (u == p && eqpre[i] < sel->remaining)) ? 1 : 0;
  }
}

__global__ void build_idx(const int* __restrict__ kept, const int* __restrict__ npre,
                          int* __restrict__ newid, int* __restrict__ idx, int n) {
  int i = blockIdx.x * 256 + threadIdx.x;
  if (i < n && kept[i]) {
    int nid = npre[i];
    newid[i] = nid;
    idx[nid] = i;
  }
}

__global__ void gather_rows(const double* __restrict__ xs, const int* __restrict__ idx,
                            double* __restrict__ xo, int k) {
  int i = blockIdx.x * 256 + threadIdx.x;
  if (i < k * 128) xo[i] = xs[(size_t)idx[i >> 7] * 128 + (i & 127)];
}

__global__ void edge_compact(const int* __restrict__ src, const int* __restrict__ dst,
                             const int* mptr, int mstat, const int* __restrict__ kept,
                             const int* __restrict__ newid, int* __restrict__ nsrc,
                             int* __restrict__ ndst, int* __restrict__ mN, int cap) {
  int m = mptr ? ((*mptr < mstat) ? *mptr : mstat) : mstat;
  int e = blockIdx.x * 256 + threadIdx.x;
  if (e < m) {
    int s = src[e], d = dst[e];
    if (kept[s] && kept[d]) {
      int pos = atomicAdd(mN, 1);
      if (pos < cap) { nsrc[pos] = newid[s]; ndst[pos] = newid[d]; }
    }
  }
}

__global__ void scatter_add_rows(float* __restrict__ h, const float* __restrict__ t,
                                 const int* __restrict__ idx, int k) {
  int i = blockIdx.x * 256 + threadIdx.x;
  if (i < k * 128) h[(size_t)idx[i >> 7] * 128 + (i & 127)] += t[i];
}

// ---------------- host ----------------

extern "C" void kernel_launch(void* const* d_in, const int* in_sizes, int n_in,
                              void* d_out, int out_size, void* d_ws, size_t ws_size,
                              hipStream_t stream) {
  (void)in_sizes; (void)out_size;
  if (n_in < 17) return;
  const float* x_in   = (const float*)d_in[0];
  const int*   ei     = (const int*)  d_in[1];
  const float* in_W   = (const float*)d_in[2];
  const float* in_b   = (const float*)d_in[3];
  const float* dn_W   = (const float*)d_in[4];
  const float* dn_b   = (const float*)d_in[5];
  const float* dn_g   = (const float*)d_in[6];
  const float* dn_bt  = (const float*)d_in[7];
  const float* pool_w = (const float*)d_in[8];
  const float* bot_W  = (const float*)d_in[9];
  const float* bot_b  = (const float*)d_in[10];
  const float* up_W   = (const float*)d_in[11];
  const float* up_b   = (const float*)d_in[12];
  const float* up_g   = (const float*)d_in[13];
  const float* up_bt  = (const float*)d_in[14];
  const float* out_W  = (const float*)d_in[15];
  const float* out_b  = (const float*)d_in[16];
  float* outp = (float*)d_out;

  char* base = (char*)d_ws;
  size_t off = 0;
  auto alloc = [&](size_t b) -> void* {
    void* r = base + off;
    off = (off + b + 255) & ~(size_t)255;
    return r;
  };
  // Two big fp64 ping-pong buffers (102.4 MB each); fp32 skip snapshots alias
  // their dead regions per the liveness schedule below.
  double* bufA = (double*)alloc((size_t)N0_ * 128 * 8);
  double* bufB = (double*)alloc((size_t)N0_ * 128 * 8);
  float* xs0f = (float*)((char*)bufB + HALF_BYTES);   // 51.2 MB  (B upper half)
  float* xs1f = (float*)((char*)bufA + HALF_BYTES);   // 25.6 MB  (A[51.2,76.8))
  float* xs2f = (float*)((char*)bufA + HALF_BYTES + 25600000ULL); // 12.8 MB

  int* src1 = (int*)alloc((size_t)CAP1 * 4); int* dst1 = (int*)alloc((size_t)CAP1 * 4);
  int* src2 = (int*)alloc((size_t)CAP2 * 4); int* dst2 = (int*)alloc((size_t)CAP2 * 4);
  int* src3 = (int*)alloc((size_t)CAP3 * 4); int* dst3 = (int*)alloc((size_t)CAP3 * 4);
  int* csrs0 = (int*)alloc((size_t)EDG * 4);
  int* csrs1 = (int*)alloc((size_t)CAP1 * 4);
  int* csrs2 = (int*)alloc((size_t)CAP2 * 4);
  int* csrs3 = (int*)alloc((size_t)CAP3 * 4);
  double* csrw0 = (double*)alloc((size_t)EDG * 8);
  double* csrw1 = (double*)alloc((size_t)CAP1 * 8);
  double* csrw2 = (double*)alloc((size_t)CAP2 * 8);
  double* csrw3 = (double*)alloc((size_t)CAP3 * 8);
  int* csro0 = (int*)alloc((size_t)(N0_ + 1) * 4);
  int* csro1 = (int*)alloc((size_t)(N1_ + 1) * 4);
  int* csro2 = (int*)alloc((size_t)(N2_ + 1) * 4);
  int* csro3 = (int*)alloc((size_t)(N3_ + 1) * 4);
  double* dinv0 = (double*)alloc((size_t)N0_ * 8); double* dgi0 = (double*)alloc((size_t)N0_ * 8);
  double* dinv1 = (double*)alloc((size_t)N1_ * 8); double* dgi1 = (double*)alloc((size_t)N1_ * 8);
  double* dinv2 = (double*)alloc((size_t)N2_ * 8); double* dgi2 = (double*)alloc((size_t)N2_ * 8);
  double* dinv3 = (double*)alloc((size_t)N3_ * 8); double* dgi3 = (double*)alloc((size_t)N3_ * 8);
  ull* keys = (ull*)alloc((size_t)N0_ * 8);
  int* eqf   = (int*)alloc((size_t)N0_ * 4);
  int* eqpre = (int*)alloc((size_t)(N0_ + 1) * 4);
  int* kept  = (int*)alloc((size_t)N0_ * 4);
  int* npre  = (int*)alloc((size_t)(N0_ + 1) * 4);
  int* newid = (int*)alloc((size_t)N0_ * 4);
  int* degcnt = (int*)alloc((size_t)N0_ * 4);
  int* cursor = (int*)alloc((size_t)N0_ * 4);
  int* idx0 = (int*)alloc((size_t)N1_ * 4);
  int* idx1 = (int*)alloc((size_t)N2_ * 4);
  int* idx2 = (int*)alloc((size_t)N3_ * 4);
  int* hist = (int*)alloc(8 * 256 * 4);
  Sel* sel  = (Sel*)alloc(256);
  int* mcnt = (int*)alloc(256);
  double* bns = (double*)alloc((size_t)256 * 256 * 8);  // per-block BN partials
  double* ssb = (double*)alloc(256 * 8);
  double* wn  = (double*)alloc(256);
  if (off > ws_size) {  // signal: absmax will be ~ws_size
    sentinel_k<<<1, 64, 0, stream>>>(outp, (float)ws_size);
    return;
  }

  const int nL[4]   = {N0_, N1_, N2_, N3_};
  const int capL[4] = {EDG, CAP1, CAP2, CAP3};
  const int* srcL[4] = {ei, src1, src2, src3};
  const int* dstL[4] = {ei + EDG, dst1, dst2, dst3};
  int* wsrcL[4] = {nullptr, src1, src2, src3};
  int* wdstL[4] = {nullptr, dst1, dst2, dst3};
  int* csrsL[4] = {csrs0, csrs1, csrs2, csrs3};
  double* csrwL[4] = {csrw0, csrw1, csrw2, csrw3};
  int* csroL[4] = {csro0, csro1, csro2, csro3};
  double* dinvL[4] = {dinv0, dinv1, dinv2, dinv3};
  double* dgiL[4]  = {dgi0, dgi1, dgi2, dgi3};
  int* mptrL[4] = {nullptr, mcnt, mcnt + 1, mcnt + 2};
  int* idxL[3] = {idx0, idx1, idx2};

  auto cdiv = [](int a, int b) { return (a + b - 1) / b; };

  auto build_csr = [&](int L) {
    hipMemsetAsync(degcnt, 0, (size_t)nL[L] * 4, stream);
    count_deg<<<cdiv(capL[L], 256), 256, 0, stream>>>(dstL[L], mptrL[L], capL[L], degcnt);
    fin_deg<<<cdiv(nL[L], 256), 256, 0, stream>>>(degcnt, dinvL[L], dgiL[L], nL[L]);
    scan_excl<<<1, 1024, 0, stream>>>(degcnt, csroL[L], nL[L]);
    hipMemsetAsync(cursor, 0, (size_t)nL[L] * 4, stream);
    csr_fill<<<cdiv(capL[L], 256), 256, 0, stream>>>(srcL[L], dstL[L], mptrL[L], capL[L],
        csroL[L], cursor, csrsL[L], csrwL[L], dinvL[L]);
  };

  auto bn_d = [&](double* xp, int n, const float* g, const float* b, float* snap) {
    bn_stats<double><<<256, 256, 0, stream>>>(xp, n, bns);
    bn_final<<<1, 128, 0, stream>>>(bns, g, b, 1.0 / (double)n, ssb);
    bn_apply_relu<double><<<cdiv(n * 128, 256), 256, 0, stream>>>(xp, ssb, snap,
                                                                  (size_t)n * 128);
  };
  auto bn_f = [&](float* xp, int n, const float* g, const float* b) {
    bn_stats<float><<<256, 256, 0, stream>>>(xp, n, bns);
    bn_final<<<1, 128, 0, stream>>>(bns, g, b, 1.0 / (double)n, ssb);
    bn_apply_relu<float><<<cdiv(n * 128, 256), 256, 0, stream>>>(xp, ssb, nullptr,
                                                                 (size_t)n * 128);
  };

  // pool level i: xcur (n_i x128 fp64) -> keys/top-k; gather kept rows (fp64)
  // into xnext; compact edges; build level i+1 CSR. (fp32 snapshot already
  // written by bn_apply_relu.)
  auto pool = [&](int i, const double* xcur, double* xnext) {
    int n = nL[i], k = nL[i + 1];
    wnorm_k<<<1, 128, 0, stream>>>(pool_w + i * 128, wn);
    score_key_k<<<cdiv(n, 2), 256, 0, stream>>>(xcur, pool_w + i * 128, wn, keys, n);
    sel_init<<<1, 64, 0, stream>>>(sel, k);
    hipMemsetAsync(hist, 0, 8 * 256 * 4, stream);
    for (int p = 0; p < 8; ++p) {
      int shift = 56 - 8 * p;
      rs_hist<<<cdiv(n, 256), 256, 0, stream>>>(keys, n, sel, shift, p, hist + p * 256);
      rs_pick<<<1, 256, 0, stream>>>(hist + p * 256, sel, shift);
    }
    eq_flags<<<cdiv(n, 256), 256, 0, stream>>>(keys, sel, eqf, n);
    scan_excl<<<1, 1024, 0, stream>>>(eqf, eqpre, n);
    kept_flags<<<cdiv(n, 256), 256, 0, stream>>>(keys, sel, eqpre, kept, n);
    scan_excl<<<1, 1024, 0, stream>>>(kept, npre, n);
    build_idx<<<cdiv(n, 256), 256, 0, stream>>>(kept, npre, newid, idxL[i], n);
    gather_rows<<<cdiv(k * 128, 256), 256, 0, stream>>>(xcur, idxL[i], xnext, k);
    hipMemsetAsync(mptrL[i + 1], 0, 4, stream);
    edge_compact<<<cdiv(capL[i], 256), 256, 0, stream>>>(srcL[i], dstL[i], mptrL[i], capL[i],
        kept, newid, wsrcL[i + 1], wdstL[i + 1], mptrL[i + 1], capL[i + 1]);
    build_csr(i + 1);
  };

  // ---- level 0 CSR + initial conv (agg-first: agg(x W)+b = (agg x) W + b) ----
  build_csr(0);
  agg_conv<float, double, false><<<cdiv(N0_, 2), 256, 0, stream>>>(
      x_in, csro0, csrs0, csrw0, dinv0, dgi0, nullptr, bufB, N0_);
  matmul128<double, double><<<cdiv(N0_, 64), 256, 0, stream>>>(bufB, in_W, in_b, bufA, N0_);

  // ---- down level 0: x in A, h in B, y back to A; xs0f -> B upper; x1 -> B lower ----
  matmul128<double, double><<<cdiv(N0_, 64), 256, 0, stream>>>(bufA, dn_W, nullptr, bufB, N0_);
  agg_conv<double, double, false><<<cdiv(N0_, 2), 256, 0, stream>>>(
      bufB, csro0, csrs0, csrw0, dinv0, dgi0, dn_b, bufA, N0_);
  bn_d(bufA, N0_, dn_g, dn_bt, xs0f);
  pool(0, bufA, bufB);

  // ---- down level 1: x in B lower, h in A lower, y back to B; xs1f -> A+51.2M ----
  matmul128<double, double><<<cdiv(N1_, 64), 256, 0, stream>>>(bufB, dn_W + 16384, nullptr, bufA, N1_);
  agg_conv<double, double, false><<<cdiv(N1_, 2), 256, 0, stream>>>(
      bufA, csro1, csrs1, csrw1, dinv1, dgi1, dn_b + 128, bufB, N1_);
  bn_d(bufB, N1_, dn_g + 128, dn_bt + 128, xs1f);
  pool(1, bufB, bufA);

  // ---- down level 2: x in A lower, h in B lower, y back to A; xs2f -> A+76.8M ----
  matmul128<double, double><<<cdiv(N2_, 64), 256, 0, stream>>>(bufA, dn_W + 32768, nullptr, bufB, N2_);
  agg_conv<double, double, false><<<cdiv(N2_, 2), 256, 0, stream>>>(
      bufB, csro2, csrs2, csrw2, dinv2, dgi2, dn_b + 256, bufA, N2_);
  bn_d(bufA, N2_, dn_g + 256, dn_bt + 256, xs2f);
  pool(2, bufA, bufB);

  // ---- bottom: x3 in B lower, h3 -> A lower, z3 (fp32, relu) -> B lower ----
  matmul128<double, double><<<cdiv(N3_, 64), 256, 0, stream>>>(bufB, bot_W, nullptr, bufA, N3_);
  float* zf = (float*)bufB;
  float* hf = (float*)bufA;
  float* tf = outp;  // d_out as scratch until final write (fully overwritten)
  agg_conv<double, float, true><<<cdiv(N3_, 2), 256, 0, stream>>>(
      bufA, csro3, csrs3, csrw3, dinv3, dgi3, bot_b, zf, N3_);

  // ---- up path (fp32): z in B lower, hf in A lower ----
  for (int u = 0; u < 3; ++u) {
    int l = 2 - u;
    int nl = nL[l], nz = nL[l + 1];
    const float* Wt = up_W + u * 32768;          // rows [0:128)  -> unpooled part
    const float* Wb = up_W + u * 32768 + 16384;  // rows [128:256)-> skip part
    const float* xsf = (u == 0) ? xs2f : (u == 1) ? xs1f : xs0f;
    matmul128<float, float><<<cdiv(nz, 64), 256, 0, stream>>>(zf, Wt, nullptr, tf, nz);
    matmul128<float, float><<<cdiv(nl, 64), 256, 0, stream>>>(xsf, Wb, nullptr, hf, nl);
    scatter_add_rows<<<cdiv(nz * 128, 256), 256, 0, stream>>>(hf, tf, idxL[l], nz);
    agg_conv<float, float, false><<<cdiv(nl, 2), 256, 0, stream>>>(
        hf, csroL[l], csrsL[l], csrwL[l], dinvL[l], dgiL[l], up_b + u * 128, zf, nl);
    bn_f(zf, nl, up_g + u * 128, up_bt + u * 128);
  }

  // ---- final conv -> d_out ----
  matmul128<float, float><<<cdiv(N0_, 64), 256, 0, stream>>>(zf, out_W, nullptr, hf, N0_);
  agg_conv<float, float, false><<<cdiv(N0_, 2), 256, 0, stream>>>(
      hf, csro0, csrs0, csrw0, dinv0, dgi0, out_b, outp, N0_);
}

// Round 4
// 4480.585 us; speedup vs baseline: 1.2179x; 1.0592x over previous
//
#include <hip/hip_runtime.h>

typedef unsigned long long ull;

#define N0_ 100000
#define N1_ 50000
#define N2_ 25000
#define N3_ 12500
#define EDG 1600000
#define CAP1 600000
#define CAP2 200000
#define CAP3 80000

#define HALF_BYTES 51200000ULL   // N0_*128*4 = half of a big fp64 buffer

struct Sel { ull prefix; int remaining; };

// ---------------- kernels ----------------

__global__ void sentinel_k(float* o, float v) { if (threadIdx.x == 0) o[0] = v; }

// C[n,128] = A[n,128] @ W[128,128] (+bias), ACC-typed accumulate. 64 rows/block.
template <typename TA, typename TC, typename ACC>
__global__ __launch_bounds__(256) void matmul128(const TA* __restrict__ A,
    const float* __restrict__ W, const float* __restrict__ bias,
    TC* __restrict__ C, int n) {
  __shared__ ACC Al[64 * 33];
  __shared__ ACC Wl[32 * 128];
  int tid = threadIdx.x;
  int colb = tid & 31;        // cols colb, colb+32, colb+64, colb+96
  int rg = tid >> 5;          // 0..7 -> rows rg*8..rg*8+7
  int row0 = blockIdx.x * 64;
  ACC acc[8][4];
#pragma unroll
  for (int r = 0; r < 8; ++r)
#pragma unroll
    for (int j = 0; j < 4; ++j) acc[r][j] = (ACC)0;
  for (int kt = 0; kt < 128; kt += 32) {
    for (int i = tid; i < 64 * 32; i += 256) {
      int r = i >> 5, kk = i & 31;
      int row = row0 + r;
      Al[r * 33 + kk] = (row < n) ? (ACC)A[(size_t)row * 128 + kt + kk] : (ACC)0;
    }
    for (int i = tid; i < 32 * 128; i += 256) {
      int kk = i >> 7, c = i & 127;
      Wl[i] = (ACC)W[(size_t)(kt + kk) * 128 + c];
    }
    __syncthreads();
#pragma unroll 4
    for (int kk = 0; kk < 32; ++kk) {
      ACC b0 = Wl[kk * 128 + colb];
      ACC b1 = Wl[kk * 128 + colb + 32];
      ACC b2 = Wl[kk * 128 + colb + 64];
      ACC b3 = Wl[kk * 128 + colb + 96];
#pragma unroll
      for (int r = 0; r < 8; ++r) {
        ACC a = Al[(rg * 8 + r) * 33 + kk];
        acc[r][0] += a * b0; acc[r][1] += a * b1;
        acc[r][2] += a * b2; acc[r][3] += a * b3;
      }
    }
    __syncthreads();
  }
  ACC bb0 = 0, bb1 = 0, bb2 = 0, bb3 = 0;
  if (bias) {
    bb0 = (ACC)bias[colb]; bb1 = (ACC)bias[colb + 32];
    bb2 = (ACC)bias[colb + 64]; bb3 = (ACC)bias[colb + 96];
  }
  for (int r = 0; r < 8; ++r) {
    int row = row0 + rg * 8 + r;
    if (row < n) {
      size_t o = (size_t)row * 128 + colb;
      C[o] = (TC)(acc[r][0] + bb0); C[o + 32] = (TC)(acc[r][1] + bb1);
      C[o + 64] = (TC)(acc[r][2] + bb2); C[o + 96] = (TC)(acc[r][3] + bb3);
    }
  }
}

// y[i,c] = di * sum_p h[src_p,c]*csrw[p] + h[i,c]*dgi[i] + b[c]
// unroll-8 neighbor loop: 8 independent row-gathers in flight per wave.
template <typename TH, typename TY, bool RELU>
__global__ __launch_bounds__(256) void agg_conv(const TH* __restrict__ h,
    const int* __restrict__ off, const int* __restrict__ csrc,
    const double* __restrict__ csrw,
    const double* __restrict__ dinv, const double* __restrict__ dgi,
    const float* __restrict__ bias, TY* __restrict__ y, int n) {
  int c = threadIdx.x & 127;
  int node = blockIdx.x * 2 + (threadIdx.x >> 7);
  if (node >= n) return;
  double di = dinv[node];
  double self = (double)h[(size_t)node * 128 + c] * dgi[node];
  double accA = 0.0, accB = 0.0;
  int p = off[node], p1 = off[node + 1];
  for (; p + 8 <= p1; p += 8) {
    int s0 = csrc[p + 0], s1 = csrc[p + 1], s2 = csrc[p + 2], s3 = csrc[p + 3];
    int s4 = csrc[p + 4], s5 = csrc[p + 5], s6 = csrc[p + 6], s7 = csrc[p + 7];
    double w0 = csrw[p + 0], w1 = csrw[p + 1], w2 = csrw[p + 2], w3 = csrw[p + 3];
    double w4 = csrw[p + 4], w5 = csrw[p + 5], w6 = csrw[p + 6], w7 = csrw[p + 7];
    double v0 = (double)h[(size_t)s0 * 128 + c];
    double v1 = (double)h[(size_t)s1 * 128 + c];
    double v2 = (double)h[(size_t)s2 * 128 + c];
    double v3 = (double)h[(size_t)s3 * 128 + c];
    double v4 = (double)h[(size_t)s4 * 128 + c];
    double v5 = (double)h[(size_t)s5 * 128 + c];
    double v6 = (double)h[(size_t)s6 * 128 + c];
    double v7 = (double)h[(size_t)s7 * 128 + c];
    accA += v0 * w0; accB += v1 * w1; accA += v2 * w2; accB += v3 * w3;
    accA += v4 * w4; accB += v5 * w5; accA += v6 * w6; accB += v7 * w7;
  }
  for (; p + 4 <= p1; p += 4) {
    int s0 = csrc[p + 0], s1 = csrc[p + 1], s2 = csrc[p + 2], s3 = csrc[p + 3];
    double w0 = csrw[p + 0], w1 = csrw[p + 1], w2 = csrw[p + 2], w3 = csrw[p + 3];
    double v0 = (double)h[(size_t)s0 * 128 + c];
    double v1 = (double)h[(size_t)s1 * 128 + c];
    double v2 = (double)h[(size_t)s2 * 128 + c];
    double v3 = (double)h[(size_t)s3 * 128 + c];
    accA += v0 * w0; accB += v1 * w1; accA += v2 * w2; accB += v3 * w3;
  }
  for (; p < p1; ++p)
    accA += (double)h[(size_t)csrc[p] * 128 + c] * csrw[p];
  double r = (accA + accB) * di + self + (bias ? (double)bias[c] : 0.0);
  if (RELU) r = r > 0.0 ? r : 0.0;
  y[(size_t)node * 128 + c] = (TY)r;
}

__global__ void count_deg(const int* __restrict__ dst, const int* mptr, int mstat,
                          int* __restrict__ cnt) {
  int m = mptr ? ((*mptr < mstat) ? *mptr : mstat) : mstat;
  int e = blockIdx.x * 256 + threadIdx.x;
  if (e < m) atomicAdd(&cnt[dst[e]], 1);
}

__global__ void fin_deg(const int* __restrict__ cnt, double* __restrict__ dinv,
                        double* __restrict__ dgi, int n) {
  int i = blockIdx.x * 256 + threadIdx.x;
  if (i < n) {
    double d = 1.0 + (double)cnt[i];
    dinv[i] = 1.0 / sqrt(d);
    dgi[i] = 1.0 / d;
  }
}

__global__ __launch_bounds__(1024) void scan_excl(const int* __restrict__ in,
                                                  int* __restrict__ out, int n) {
  __shared__ int ls[1024];
  int t = threadIdx.x;
  int chunk = (n + 1023) >> 10;
  int base = t * chunk;
  int s = 0;
  for (int j = 0; j < chunk; ++j) { int i = base + j; if (i < n) s += in[i]; }
  ls[t] = s; __syncthreads();
  for (int d = 1; d < 1024; d <<= 1) {
    int v = (t >= d) ? ls[t - d] : 0;
    __syncthreads();
    ls[t] += v;
    __syncthreads();
  }
  int run = ls[t] - s;
  for (int j = 0; j < chunk; ++j) {
    int i = base + j;
    if (i < n) { out[i] = run; run += in[i]; }
  }
  if (t == 1023) out[n] = ls[1023];
}

__global__ void csr_fill(const int* __restrict__ src, const int* __restrict__ dst,
                         const int* mptr, int mstat, const int* __restrict__ off,
                         int* __restrict__ cursor, int* __restrict__ csrs,
                         double* __restrict__ csrw, const double* __restrict__ dinv) {
  int m = mptr ? ((*mptr < mstat) ? *mptr : mstat) : mstat;
  int e = blockIdx.x * 256 + threadIdx.x;
  if (e < m) {
    int d = dst[e];
    int s = src[e];
    int pos = off[d] + atomicAdd(&cursor[d], 1);
    csrs[pos] = s;
    csrw[pos] = dinv[s];
  }
}

// fixed grid of 256 blocks; deterministic per-block partials (no atomics).
template <typename T>
__global__ __launch_bounds__(256) void bn_stats(const T* __restrict__ x, int n,
                                                double* __restrict__ part) {
  __shared__ double lsum[256], lsq[256];
  int c = threadIdx.x & 127, half = threadIdx.x >> 7;
  double s = 0, q = 0;
  for (int row = blockIdx.x * 2 + half; row < n; row += 512) {
    double v = (double)x[(size_t)row * 128 + c];
    s += v; q += v * v;
  }
  lsum[threadIdx.x] = s; lsq[threadIdx.x] = q;
  __syncthreads();
  if (half == 0) {
    part[blockIdx.x * 256 + c] = lsum[c] + lsum[c + 128];
    part[blockIdx.x * 256 + 128 + c] = lsq[c] + lsq[c + 128];
  }
}

__global__ void bn_final(const double* __restrict__ part, const float* __restrict__ g,
                         const float* __restrict__ beta, double invn,
                         double* __restrict__ ss) {
  int c = threadIdx.x;  // 128
  double s = 0, q = 0;
  for (int b = 0; b < 256; ++b) {
    s += part[b * 256 + c];
    q += part[b * 256 + 128 + c];
  }
  double m = s * invn;
  double v = q * invn - m * m;
  double sc = (double)g[c] / sqrt(v + 1e-5);
  ss[c] = sc;
  ss[128 + c] = (double)beta[c] - m * sc;
}

// apply BN+ReLU in place; optionally write fp32 snapshot (skip connection).
template <typename T>
__global__ void bn_apply_relu(T* __restrict__ x, const double* __restrict__ ss,
                              float* __restrict__ snap, size_t total) {
  size_t i = (size_t)blockIdx.x * 256 + threadIdx.x;
  if (i < total) {
    int c = (int)(i & 127);
    double v = (double)x[i] * ss[c] + ss[128 + c];
    v = v > 0.0 ? v : 0.0;
    x[i] = (T)v;
    if (snap) snap[i] = (float)v;
  }
}

__global__ void wnorm_k(const float* __restrict__ w, double* __restrict__ wn) {
  __shared__ double red[128];
  int c = threadIdx.x;
  double v = (double)w[c];
  red[c] = v * v;
  __syncthreads();
  for (int s = 64; s > 0; s >>= 1) { if (c < s) red[c] += red[c + s]; __syncthreads(); }
  if (c == 0) wn[0] = sqrt(red[0]);
}

__global__ __launch_bounds__(256) void score_key_k(const double* __restrict__ x,
    const float* __restrict__ w, const double* __restrict__ wn,
    ull* __restrict__ keys, int n) {
  __shared__ double red[256];
  int c = threadIdx.x & 127;
  int node = blockIdx.x * 2 + (threadIdx.x >> 7);
  double p = 0.0;
  if (node < n) p = x[(size_t)node * 128 + c] * (double)w[c];
  red[threadIdx.x] = p;
  __syncthreads();
  for (int s = 64; s > 0; s >>= 1) {
    if (c < s) red[threadIdx.x] += red[threadIdx.x + s];
    __syncthreads();
  }
  if (c == 0 && node < n) {
    double sc = tanh(red[threadIdx.x] / wn[0]);
    ull u = (ull)__double_as_longlong(sc);
    u = (u >> 63) ? ~u : (u | 0x8000000000000000ULL);
    keys[node] = u;
  }
}

__global__ void sel_init(Sel* sel, int k) {
  if (threadIdx.x == 0) { sel->prefix = 0ULL; sel->remaining = k; }
}

__global__ void rs_hist(const ull* __restrict__ keys, int n, const Sel* __restrict__ sel,
                        int shift, int pass, int* __restrict__ hist) {
  __shared__ int lh[256];
  lh[threadIdx.x] = 0;
  __syncthreads();
  int i = blockIdx.x * 256 + threadIdx.x;
  if (i < n) {
    ull k = keys[i];
    bool ok = (pass == 0) || (((k ^ sel->prefix) >> (shift + 8)) == 0);
    if (ok) atomicAdd(&lh[(int)((k >> shift) & 255)], 1);
  }
  __syncthreads();
  if (lh[threadIdx.x]) atomicAdd(&hist[threadIdx.x], lh[threadIdx.x]);
}

__global__ void rs_pick(const int* __restrict__ hist, Sel* sel, int shift) {
  __shared__ int lh[256];
  lh[threadIdx.x] = hist[threadIdx.x];
  __syncthreads();
  if (threadIdx.x == 0) {
    int rem = sel->remaining;
    for (int b = 255; b >= 0; --b) {
      int c = lh[b];
      if (c >= rem) { sel->prefix |= ((ull)b) << shift; break; }
      rem -= c;
    }
    sel->remaining = rem;
  }
}

__global__ void eq_flags(const ull* __restrict__ keys, const Sel* __restrict__ sel,
                         int* __restrict__ eqf, int n) {
  int i = blockIdx.x * 256 + threadIdx.x;
  if (i < n) eqf[i] = (keys[i] == sel->prefix) ? 1 : 0;
}

__global__ void kept_flags(const ull* __restrict__ keys, const Sel* __restrict__ sel,
                           const int* __restrict__ eqpre, int* __restrict__ kept, int n) {
  int i = blockIdx.x * 256 + threadIdx.x;
  if (i < n) {
    ull u = keys[i], p = sel->prefix;
    kept[i] = (u > p || (u == p && eqpre[i] < sel->remaining)) ? 1 : 0;
  }
}

__global__ void build_idx(const int* __restrict__ kept, const int* __restrict__ npre,
                          int* __restrict__ newid, int* __restrict__ idx, int n) {
  int i = blockIdx.x * 256 + threadIdx.x;
  if (i < n && kept[i]) {
    int nid = npre[i];
    newid[i] = nid;
    idx[nid] = i;
  }
}

__global__ void gather_rows(const double* __restrict__ xs, const int* __restrict__ idx,
                            double* __restrict__ xo, int k) {
  int i = blockIdx.x * 256 + threadIdx.x;
  if (i < k * 128) xo[i] = xs[(size_t)idx[i >> 7] * 128 + (i & 127)];
}

// wave-aggregated compaction: one atomicAdd per wave (64x fewer atomics).
__global__ void edge_compact(const int* __restrict__ src, const int* __restrict__ dst,
                             const int* mptr, int mstat, const int* __restrict__ kept,
                             const int* __restrict__ newid, int* __restrict__ nsrc,
                             int* __restrict__ ndst, int* __restrict__ mN, int cap) {
  int m = mptr ? ((*mptr < mstat) ? *mptr : mstat) : mstat;
  int e = blockIdx.x * 256 + threadIdx.x;
  int lane = threadIdx.x & 63;
  bool keep = false;
  int s = 0, d = 0;
  if (e < m) {
    s = src[e]; d = dst[e];
    keep = kept[s] && kept[d];
  }
  ull mask = __ballot(keep);
  int cnt = __popcll(mask);
  int base = 0;
  if (lane == 0 && cnt > 0) base = atomicAdd(mN, cnt);
  base = __shfl(base, 0);
  if (keep) {
    int pos = base + __popcll(mask & ((1ULL << lane) - 1ULL));
    if (pos < cap) { nsrc[pos] = newid[s]; ndst[pos] = newid[d]; }
  }
}

__global__ void scatter_add_rows(float* __restrict__ h, const float* __restrict__ t,
                                 const int* __restrict__ idx, int k) {
  int i = blockIdx.x * 256 + threadIdx.x;
  if (i < k * 128) h[(size_t)idx[i >> 7] * 128 + (i & 127)] += t[i];
}

// ---------------- host ----------------

extern "C" void kernel_launch(void* const* d_in, const int* in_sizes, int n_in,
                              void* d_out, int out_size, void* d_ws, size_t ws_size,
                              hipStream_t stream) {
  (void)in_sizes; (void)out_size;
  if (n_in < 17) return;
  const float* x_in   = (const float*)d_in[0];
  const int*   ei     = (const int*)  d_in[1];
  const float* in_W   = (const float*)d_in[2];
  const float* in_b   = (const float*)d_in[3];
  const float* dn_W   = (const float*)d_in[4];
  const float* dn_b   = (const float*)d_in[5];
  const float* dn_g   = (const float*)d_in[6];
  const float* dn_bt  = (const float*)d_in[7];
  const float* pool_w = (const float*)d_in[8];
  const float* bot_W  = (const float*)d_in[9];
  const float* bot_b  = (const float*)d_in[10];
  const float* up_W   = (const float*)d_in[11];
  const float* up_b   = (const float*)d_in[12];
  const float* up_g   = (const float*)d_in[13];
  const float* up_bt  = (const float*)d_in[14];
  const float* out_W  = (const float*)d_in[15];
  const float* out_b  = (const float*)d_in[16];
  float* outp = (float*)d_out;

  char* base = (char*)d_ws;
  size_t off = 0;
  auto alloc = [&](size_t b) -> void* {
    void* r = base + off;
    off = (off + b + 255) & ~(size_t)255;
    return r;
  };
  // Two big fp64 ping-pong buffers (102.4 MB each); fp32 skip snapshots alias
  // their dead regions per the liveness schedule below.
  double* bufA = (double*)alloc((size_t)N0_ * 128 * 8);
  double* bufB = (double*)alloc((size_t)N0_ * 128 * 8);
  float* xs0f = (float*)((char*)bufB + HALF_BYTES);   // 51.2 MB  (B upper half)
  float* xs1f = (float*)((char*)bufA + HALF_BYTES);   // 25.6 MB  (A[51.2,76.8))
  float* xs2f = (float*)((char*)bufA + HALF_BYTES + 25600000ULL); // 12.8 MB

  int* src1 = (int*)alloc((size_t)CAP1 * 4); int* dst1 = (int*)alloc((size_t)CAP1 * 4);
  int* src2 = (int*)alloc((size_t)CAP2 * 4); int* dst2 = (int*)alloc((size_t)CAP2 * 4);
  int* src3 = (int*)alloc((size_t)CAP3 * 4); int* dst3 = (int*)alloc((size_t)CAP3 * 4);
  int* csrs0 = (int*)alloc((size_t)EDG * 4);
  int* csrs1 = (int*)alloc((size_t)CAP1 * 4);
  int* csrs2 = (int*)alloc((size_t)CAP2 * 4);
  int* csrs3 = (int*)alloc((size_t)CAP3 * 4);
  double* csrw0 = (double*)alloc((size_t)EDG * 8);
  double* csrw1 = (double*)alloc((size_t)CAP1 * 8);
  double* csrw2 = (double*)alloc((size_t)CAP2 * 8);
  double* csrw3 = (double*)alloc((size_t)CAP3 * 8);
  int* csro0 = (int*)alloc((size_t)(N0_ + 1) * 4);
  int* csro1 = (int*)alloc((size_t)(N1_ + 1) * 4);
  int* csro2 = (int*)alloc((size_t)(N2_ + 1) * 4);
  int* csro3 = (int*)alloc((size_t)(N3_ + 1) * 4);
  double* dinv0 = (double*)alloc((size_t)N0_ * 8); double* dgi0 = (double*)alloc((size_t)N0_ * 8);
  double* dinv1 = (double*)alloc((size_t)N1_ * 8); double* dgi1 = (double*)alloc((size_t)N1_ * 8);
  double* dinv2 = (double*)alloc((size_t)N2_ * 8); double* dgi2 = (double*)alloc((size_t)N2_ * 8);
  double* dinv3 = (double*)alloc((size_t)N3_ * 8); double* dgi3 = (double*)alloc((size_t)N3_ * 8);
  ull* keys = (ull*)alloc((size_t)N0_ * 8);
  int* eqf   = (int*)alloc((size_t)N0_ * 4);
  int* eqpre = (int*)alloc((size_t)(N0_ + 1) * 4);
  int* kept  = (int*)alloc((size_t)N0_ * 4);
  int* npre  = (int*)alloc((size_t)(N0_ + 1) * 4);
  int* newid = (int*)alloc((size_t)N0_ * 4);
  int* degcnt = (int*)alloc((size_t)N0_ * 4);
  int* cursor = (int*)alloc((size_t)N0_ * 4);
  int* idx0 = (int*)alloc((size_t)N1_ * 4);
  int* idx1 = (int*)alloc((size_t)N2_ * 4);
  int* idx2 = (int*)alloc((size_t)N3_ * 4);
  int* hist = (int*)alloc(8 * 256 * 4);
  Sel* sel  = (Sel*)alloc(256);
  int* mcnt = (int*)alloc(256);
  double* bns = (double*)alloc((size_t)256 * 256 * 8);  // per-block BN partials
  double* ssb = (double*)alloc(256 * 8);
  double* wn  = (double*)alloc(256);
  if (off > ws_size) {  // signal: absmax will be ~ws_size
    sentinel_k<<<1, 64, 0, stream>>>(outp, (float)ws_size);
    return;
  }

  const int nL[4]   = {N0_, N1_, N2_, N3_};
  const int capL[4] = {EDG, CAP1, CAP2, CAP3};
  const int* srcL[4] = {ei, src1, src2, src3};
  const int* dstL[4] = {ei + EDG, dst1, dst2, dst3};
  int* wsrcL[4] = {nullptr, src1, src2, src3};
  int* wdstL[4] = {nullptr, dst1, dst2, dst3};
  int* csrsL[4] = {csrs0, csrs1, csrs2, csrs3};
  double* csrwL[4] = {csrw0, csrw1, csrw2, csrw3};
  int* csroL[4] = {csro0, csro1, csro2, csro3};
  double* dinvL[4] = {dinv0, dinv1, dinv2, dinv3};
  double* dgiL[4]  = {dgi0, dgi1, dgi2, dgi3};
  int* mptrL[4] = {nullptr, mcnt, mcnt + 1, mcnt + 2};
  int* idxL[3] = {idx0, idx1, idx2};

  auto cdiv = [](int a, int b) { return (a + b - 1) / b; };

  auto build_csr = [&](int L) {
    hipMemsetAsync(degcnt, 0, (size_t)nL[L] * 4, stream);
    count_deg<<<cdiv(capL[L], 256), 256, 0, stream>>>(dstL[L], mptrL[L], capL[L], degcnt);
    fin_deg<<<cdiv(nL[L], 256), 256, 0, stream>>>(degcnt, dinvL[L], dgiL[L], nL[L]);
    scan_excl<<<1, 1024, 0, stream>>>(degcnt, csroL[L], nL[L]);
    hipMemsetAsync(cursor, 0, (size_t)nL[L] * 4, stream);
    csr_fill<<<cdiv(capL[L], 256), 256, 0, stream>>>(srcL[L], dstL[L], mptrL[L], capL[L],
        csroL[L], cursor, csrsL[L], csrwL[L], dinvL[L]);
  };

  auto bn_d = [&](double* xp, int n, const float* g, const float* b, float* snap) {
    bn_stats<double><<<256, 256, 0, stream>>>(xp, n, bns);
    bn_final<<<1, 128, 0, stream>>>(bns, g, b, 1.0 / (double)n, ssb);
    bn_apply_relu<double><<<cdiv(n * 128, 256), 256, 0, stream>>>(xp, ssb, snap,
                                                                  (size_t)n * 128);
  };
  auto bn_f = [&](float* xp, int n, const float* g, const float* b) {
    bn_stats<float><<<256, 256, 0, stream>>>(xp, n, bns);
    bn_final<<<1, 128, 0, stream>>>(bns, g, b, 1.0 / (double)n, ssb);
    bn_apply_relu<float><<<cdiv(n * 128, 256), 256, 0, stream>>>(xp, ssb, nullptr,
                                                                 (size_t)n * 128);
  };

  // pool level i: xcur (n_i x128 fp64) -> keys/top-k; gather kept rows (fp64)
  // into xnext; compact edges; build level i+1 CSR.
  auto pool = [&](int i, const double* xcur, double* xnext) {
    int n = nL[i], k = nL[i + 1];
    wnorm_k<<<1, 128, 0, stream>>>(pool_w + i * 128, wn);
    score_key_k<<<cdiv(n, 2), 256, 0, stream>>>(xcur, pool_w + i * 128, wn, keys, n);
    sel_init<<<1, 64, 0, stream>>>(sel, k);
    hipMemsetAsync(hist, 0, 8 * 256 * 4, stream);
    for (int p = 0; p < 8; ++p) {
      int shift = 56 - 8 * p;
      rs_hist<<<cdiv(n, 256), 256, 0, stream>>>(keys, n, sel, shift, p, hist + p * 256);
      rs_pick<<<1, 256, 0, stream>>>(hist + p * 256, sel, shift);
    }
    eq_flags<<<cdiv(n, 256), 256, 0, stream>>>(keys, sel, eqf, n);
    scan_excl<<<1, 1024, 0, stream>>>(eqf, eqpre, n);
    kept_flags<<<cdiv(n, 256), 256, 0, stream>>>(keys, sel, eqpre, kept, n);
    scan_excl<<<1, 1024, 0, stream>>>(kept, npre, n);
    build_idx<<<cdiv(n, 256), 256, 0, stream>>>(kept, npre, newid, idxL[i], n);
    gather_rows<<<cdiv(k * 128, 256), 256, 0, stream>>>(xcur, idxL[i], xnext, k);
    hipMemsetAsync(mptrL[i + 1], 0, 4, stream);
    edge_compact<<<cdiv(capL[i], 256), 256, 0, stream>>>(srcL[i], dstL[i], mptrL[i], capL[i],
        kept, newid, wsrcL[i + 1], wdstL[i + 1], mptrL[i + 1], capL[i + 1]);
    build_csr(i + 1);
  };

  // ---- level 0 CSR + initial conv (agg-first: agg(x W)+b = (agg x) W + b) ----
  build_csr(0);
  agg_conv<float, double, false><<<cdiv(N0_, 2), 256, 0, stream>>>(
      x_in, csro0, csrs0, csrw0, dinv0, dgi0, nullptr, bufB, N0_);
  matmul128<double, double, double><<<cdiv(N0_, 64), 256, 0, stream>>>(bufB, in_W, in_b, bufA, N0_);

  // ---- down level 0: x in A, h in B, y back to A; xs0f -> B upper; x1 -> B lower ----
  matmul128<double, double, double><<<cdiv(N0_, 64), 256, 0, stream>>>(bufA, dn_W, nullptr, bufB, N0_);
  agg_conv<double, double, false><<<cdiv(N0_, 2), 256, 0, stream>>>(
      bufB, csro0, csrs0, csrw0, dinv0, dgi0, dn_b, bufA, N0_);
  bn_d(bufA, N0_, dn_g, dn_bt, xs0f);
  pool(0, bufA, bufB);

  // ---- down level 1: x in B lower, h in A lower, y back to B; xs1f -> A+51.2M ----
  matmul128<double, double, double><<<cdiv(N1_, 64), 256, 0, stream>>>(bufB, dn_W + 16384, nullptr, bufA, N1_);
  agg_conv<double, double, false><<<cdiv(N1_, 2), 256, 0, stream>>>(
      bufA, csro1, csrs1, csrw1, dinv1, dgi1, dn_b + 128, bufB, N1_);
  bn_d(bufB, N1_, dn_g + 128, dn_bt + 128, xs1f);
  pool(1, bufB, bufA);

  // ---- down level 2: x in A lower, h in B lower, y back to A; xs2f -> A+76.8M ----
  matmul128<double, double, double><<<cdiv(N2_, 64), 256, 0, stream>>>(bufA, dn_W + 32768, nullptr, bufB, N2_);
  agg_conv<double, double, false><<<cdiv(N2_, 2), 256, 0, stream>>>(
      bufB, csro2, csrs2, csrw2, dinv2, dgi2, dn_b + 256, bufA, N2_);
  bn_d(bufA, N2_, dn_g + 256, dn_bt + 256, xs2f);
  pool(2, bufA, bufB);

  // ---- bottom: x3 in B lower, h3 -> A lower, z3 (fp32, relu) -> B lower ----
  matmul128<double, double, double><<<cdiv(N3_, 64), 256, 0, stream>>>(bufB, bot_W, nullptr, bufA, N3_);
  float* zf = (float*)bufB;
  float* hf = (float*)bufA;
  float* tf = outp;  // d_out as scratch until final write (fully overwritten)
  agg_conv<double, float, true><<<cdiv(N3_, 2), 256, 0, stream>>>(
      bufA, csro3, csrs3, csrw3, dinv3, dgi3, bot_b, zf, N3_);

  // ---- up path (fp32 data + fp32 accumulate): z in B lower, hf in A lower ----
  for (int u = 0; u < 3; ++u) {
    int l = 2 - u;
    int nl = nL[l], nz = nL[l + 1];
    const float* Wt = up_W + u * 32768;          // rows [0:128)  -> unpooled part
    const float* Wb = up_W + u * 32768 + 16384;  // rows [128:256)-> skip part
    const float* xsf = (u == 0) ? xs2f : (u == 1) ? xs1f : xs0f;
    matmul128<float, float, float><<<cdiv(nz, 64), 256, 0, stream>>>(zf, Wt, nullptr, tf, nz);
    matmul128<float, float, float><<<cdiv(nl, 64), 256, 0, stream>>>(xsf, Wb, nullptr, hf, nl);
    scatter_add_rows<<<cdiv(nz * 128, 256), 256, 0, stream>>>(hf, tf, idxL[l], nz);
    agg_conv<float, float, false><<<cdiv(nl, 2), 256, 0, stream>>>(
        hf, csroL[l], csrsL[l], csrwL[l], dinvL[l], dgiL[l], up_b + u * 128, zf, nl);
    bn_f(zf, nl, up_g + u * 128, up_bt + u * 128);
  }

  // ---- final conv -> d_out ----
  matmul128<float, float, float><<<cdiv(N0_, 64), 256, 0, stream>>>(zf, out_W, nullptr, hf, N0_);
  agg_conv<float, float, false><<<cdiv(N0_, 2), 256, 0, stream>>>(
      hf, csro0, csrs0, csrw0, dinv0, dgi0, out_b, outp, N0_);
}

// Round 5
// 4023.905 us; speedup vs baseline: 1.3561x; 1.1135x over previous
//
#include <hip/hip_runtime.h>

typedef unsigned long long ull;

#define N0_ 100000
#define N1_ 50000
#define N2_ 25000
#define N3_ 12500
#define EDG 1600000
#define CAP1 600000
#define CAP2 200000
#define CAP3 80000

#define HALF_BYTES 51200000ULL   // N0_*128*4 = half of a big fp64 buffer

struct Sel { ull prefix; int remaining; };

// ---------------- kernels ----------------

__global__ void sentinel_k(float* o, float v) { if (threadIdx.x == 0) o[0] = v; }

// C[n,128] = A[n,128] @ W[128,128] (+bias), ACC-typed accumulate. 64 rows/block.
template <typename TA, typename TC, typename ACC>
__global__ __launch_bounds__(256) void matmul128(const TA* __restrict__ A,
    const float* __restrict__ W, const float* __restrict__ bias,
    TC* __restrict__ C, int n) {
  __shared__ ACC Al[64 * 33];
  __shared__ ACC Wl[32 * 128];
  int tid = threadIdx.x;
  int colb = tid & 31;        // cols colb, colb+32, colb+64, colb+96
  int rg = tid >> 5;          // 0..7 -> rows rg*8..rg*8+7
  int row0 = blockIdx.x * 64;
  ACC acc[8][4];
#pragma unroll
  for (int r = 0; r < 8; ++r)
#pragma unroll
    for (int j = 0; j < 4; ++j) acc[r][j] = (ACC)0;
  for (int kt = 0; kt < 128; kt += 32) {
    for (int i = tid; i < 64 * 32; i += 256) {
      int r = i >> 5, kk = i & 31;
      int row = row0 + r;
      Al[r * 33 + kk] = (row < n) ? (ACC)A[(size_t)row * 128 + kt + kk] : (ACC)0;
    }
    for (int i = tid; i < 32 * 128; i += 256) {
      int kk = i >> 7, c = i & 127;
      Wl[i] = (ACC)W[(size_t)(kt + kk) * 128 + c];
    }
    __syncthreads();
#pragma unroll 4
    for (int kk = 0; kk < 32; ++kk) {
      ACC b0 = Wl[kk * 128 + colb];
      ACC b1 = Wl[kk * 128 + colb + 32];
      ACC b2 = Wl[kk * 128 + colb + 64];
      ACC b3 = Wl[kk * 128 + colb + 96];
#pragma unroll
      for (int r = 0; r < 8; ++r) {
        ACC a = Al[(rg * 8 + r) * 33 + kk];
        acc[r][0] += a * b0; acc[r][1] += a * b1;
        acc[r][2] += a * b2; acc[r][3] += a * b3;
      }
    }
    __syncthreads();
  }
  ACC bb0 = 0, bb1 = 0, bb2 = 0, bb3 = 0;
  if (bias) {
    bb0 = (ACC)bias[colb]; bb1 = (ACC)bias[colb + 32];
    bb2 = (ACC)bias[colb + 64]; bb3 = (ACC)bias[colb + 96];
  }
  for (int r = 0; r < 8; ++r) {
    int row = row0 + rg * 8 + r;
    if (row < n) {
      size_t o = (size_t)row * 128 + colb;
      C[o] = (TC)(acc[r][0] + bb0); C[o + 32] = (TC)(acc[r][1] + bb1);
      C[o + 64] = (TC)(acc[r][2] + bb2); C[o + 96] = (TC)(acc[r][3] + bb3);
    }
  }
}

// y[i,c] = di * sum_p h[src_p,c]*csrw[p] + h[i,c]*dgi[i] + b[c]
// unroll-8 neighbor loop: 8 independent row-gathers in flight per wave.
template <typename TH, typename TY, bool RELU>
__global__ __launch_bounds__(256) void agg_conv(const TH* __restrict__ h,
    const int* __restrict__ off, const int* __restrict__ csrc,
    const double* __restrict__ csrw,
    const double* __restrict__ dinv, const double* __restrict__ dgi,
    const float* __restrict__ bias, TY* __restrict__ y, int n) {
  int c = threadIdx.x & 127;
  int node = blockIdx.x * 2 + (threadIdx.x >> 7);
  if (node >= n) return;
  double di = dinv[node];
  double self = (double)h[(size_t)node * 128 + c] * dgi[node];
  double accA = 0.0, accB = 0.0;
  int p = off[node], p1 = off[node + 1];
  for (; p + 8 <= p1; p += 8) {
    int s0 = csrc[p + 0], s1 = csrc[p + 1], s2 = csrc[p + 2], s3 = csrc[p + 3];
    int s4 = csrc[p + 4], s5 = csrc[p + 5], s6 = csrc[p + 6], s7 = csrc[p + 7];
    double w0 = csrw[p + 0], w1 = csrw[p + 1], w2 = csrw[p + 2], w3 = csrw[p + 3];
    double w4 = csrw[p + 4], w5 = csrw[p + 5], w6 = csrw[p + 6], w7 = csrw[p + 7];
    double v0 = (double)h[(size_t)s0 * 128 + c];
    double v1 = (double)h[(size_t)s1 * 128 + c];
    double v2 = (double)h[(size_t)s2 * 128 + c];
    double v3 = (double)h[(size_t)s3 * 128 + c];
    double v4 = (double)h[(size_t)s4 * 128 + c];
    double v5 = (double)h[(size_t)s5 * 128 + c];
    double v6 = (double)h[(size_t)s6 * 128 + c];
    double v7 = (double)h[(size_t)s7 * 128 + c];
    accA += v0 * w0; accB += v1 * w1; accA += v2 * w2; accB += v3 * w3;
    accA += v4 * w4; accB += v5 * w5; accA += v6 * w6; accB += v7 * w7;
  }
  for (; p + 4 <= p1; p += 4) {
    int s0 = csrc[p + 0], s1 = csrc[p + 1], s2 = csrc[p + 2], s3 = csrc[p + 3];
    double w0 = csrw[p + 0], w1 = csrw[p + 1], w2 = csrw[p + 2], w3 = csrw[p + 3];
    double v0 = (double)h[(size_t)s0 * 128 + c];
    double v1 = (double)h[(size_t)s1 * 128 + c];
    double v2 = (double)h[(size_t)s2 * 128 + c];
    double v3 = (double)h[(size_t)s3 * 128 + c];
    accA += v0 * w0; accB += v1 * w1; accA += v2 * w2; accB += v3 * w3;
  }
  for (; p < p1; ++p)
    accA += (double)h[(size_t)csrc[p] * 128 + c] * csrw[p];
  double r = (accA + accB) * di + self + (bias ? (double)bias[c] : 0.0);
  if (RELU) r = r > 0.0 ? r : 0.0;
  y[(size_t)node * 128 + c] = (TY)r;
}

// level-0 CSR build only
__global__ void count_deg(const int* __restrict__ dst, int m, int* __restrict__ cnt) {
  int e = blockIdx.x * 256 + threadIdx.x;
  if (e < m) atomicAdd(&cnt[dst[e]], 1);
}

__global__ void fin_deg(const int* __restrict__ cnt, double* __restrict__ dinv,
                        double* __restrict__ dgi, int n) {
  int i = blockIdx.x * 256 + threadIdx.x;
  if (i < n) {
    double d = 1.0 + (double)cnt[i];
    dinv[i] = 1.0 / sqrt(d);
    dgi[i] = 1.0 / d;
  }
}

__global__ __launch_bounds__(1024) void scan_excl(const int* __restrict__ in,
                                                  int* __restrict__ out, int n) {
  __shared__ int ls[1024];
  int t = threadIdx.x;
  int chunk = (n + 1023) >> 10;
  int base = t * chunk;
  int s = 0;
  for (int j = 0; j < chunk; ++j) { int i = base + j; if (i < n) s += in[i]; }
  ls[t] = s; __syncthreads();
  for (int d = 1; d < 1024; d <<= 1) {
    int v = (t >= d) ? ls[t - d] : 0;
    __syncthreads();
    ls[t] += v;
    __syncthreads();
  }
  int run = ls[t] - s;
  for (int j = 0; j < chunk; ++j) {
    int i = base + j;
    if (i < n) { out[i] = run; run += in[i]; }
  }
  if (t == 1023) out[n] = ls[1023];
}

__global__ void csr_fill(const int* __restrict__ src, const int* __restrict__ dst,
                         int m, const int* __restrict__ off,
                         int* __restrict__ cursor, int* __restrict__ csrs,
                         double* __restrict__ csrw, const double* __restrict__ dinv) {
  int e = blockIdx.x * 256 + threadIdx.x;
  if (e < m) {
    int d = dst[e];
    int s = src[e];
    int pos = off[d] + atomicAdd(&cursor[d], 1);
    csrs[pos] = s;
    csrw[pos] = dinv[s];
  }
}

// ---- CSR-direct next-level build (no edge list, no atomics) ----
// knid[i] = new id if kept else -1.
__global__ void next_deg(const int* __restrict__ off, const int* __restrict__ csrs,
                         const int* __restrict__ knid, int* __restrict__ ndeg, int n) {
  int d = blockIdx.x * 256 + threadIdx.x;
  if (d >= n) return;
  int nd = knid[d];
  if (nd < 0) return;
  int cnt = 0;
  int p1 = off[d + 1];
  for (int p = off[d]; p < p1; ++p) cnt += (knid[csrs[p]] >= 0) ? 1 : 0;
  ndeg[nd] = cnt;
}

__global__ void next_fill(const int* __restrict__ off, const int* __restrict__ csrs,
                          const int* __restrict__ knid, const int* __restrict__ noff,
                          const double* __restrict__ ndinv,
                          int* __restrict__ ncsrs, double* __restrict__ ncsrw, int n) {
  int d = blockIdx.x * 256 + threadIdx.x;
  if (d >= n) return;
  int nd = knid[d];
  if (nd < 0) return;
  int pos = noff[nd];
  int p1 = off[d + 1];
  for (int p = off[d]; p < p1; ++p) {
    int s = knid[csrs[p]];
    if (s >= 0) { ncsrs[pos] = s; ncsrw[pos] = ndinv[s]; ++pos; }
  }
}

// fixed grid of 256 blocks; deterministic per-block partials (no atomics).
template <typename T>
__global__ __launch_bounds__(256) void bn_stats(const T* __restrict__ x, int n,
                                                double* __restrict__ part) {
  __shared__ double lsum[256], lsq[256];
  int c = threadIdx.x & 127, half = threadIdx.x >> 7;
  double s = 0, q = 0;
  for (int row = blockIdx.x * 2 + half; row < n; row += 512) {
    double v = (double)x[(size_t)row * 128 + c];
    s += v; q += v * v;
  }
  lsum[threadIdx.x] = s; lsq[threadIdx.x] = q;
  __syncthreads();
  if (half == 0) {
    part[blockIdx.x * 256 + c] = lsum[c] + lsum[c + 128];
    part[blockIdx.x * 256 + 128 + c] = lsq[c] + lsq[c + 128];
  }
}

__global__ void bn_final(const double* __restrict__ part, const float* __restrict__ g,
                         const float* __restrict__ beta, double invn,
                         double* __restrict__ ss) {
  int c = threadIdx.x;  // 128
  double s = 0, q = 0;
  for (int b = 0; b < 256; ++b) {
    s += part[b * 256 + c];
    q += part[b * 256 + 128 + c];
  }
  double m = s * invn;
  double v = q * invn - m * m;
  double sc = (double)g[c] / sqrt(v + 1e-5);
  ss[c] = sc;
  ss[128 + c] = (double)beta[c] - m * sc;
}

// apply BN+ReLU in place; optionally write fp32 snapshot (skip connection).
template <typename T>
__global__ void bn_apply_relu(T* __restrict__ x, const double* __restrict__ ss,
                              float* __restrict__ snap, size_t total) {
  size_t i = (size_t)blockIdx.x * 256 + threadIdx.x;
  if (i < total) {
    int c = (int)(i & 127);
    double v = (double)x[i] * ss[c] + ss[128 + c];
    v = v > 0.0 ? v : 0.0;
    x[i] = (T)v;
    if (snap) snap[i] = (float)v;
  }
}

__global__ void wnorm_k(const float* __restrict__ w, double* __restrict__ wn) {
  __shared__ double red[128];
  int c = threadIdx.x;
  double v = (double)w[c];
  red[c] = v * v;
  __syncthreads();
  for (int s = 64; s > 0; s >>= 1) { if (c < s) red[c] += red[c + s]; __syncthreads(); }
  if (c == 0) wn[0] = sqrt(red[0]);
}

__global__ __launch_bounds__(256) void score_key_k(const double* __restrict__ x,
    const float* __restrict__ w, const double* __restrict__ wn,
    ull* __restrict__ keys, int n) {
  __shared__ double red[256];
  int c = threadIdx.x & 127;
  int node = blockIdx.x * 2 + (threadIdx.x >> 7);
  double p = 0.0;
  if (node < n) p = x[(size_t)node * 128 + c] * (double)w[c];
  red[threadIdx.x] = p;
  __syncthreads();
  for (int s = 64; s > 0; s >>= 1) {
    if (c < s) red[threadIdx.x] += red[threadIdx.x + s];
    __syncthreads();
  }
  if (c == 0 && node < n) {
    double sc = tanh(red[threadIdx.x] / wn[0]);
    ull u = (ull)__double_as_longlong(sc);
    u = (u >> 63) ? ~u : (u | 0x8000000000000000ULL);
    keys[node] = u;
  }
}

__global__ void sel_init(Sel* sel, int k) {
  if (threadIdx.x == 0) { sel->prefix = 0ULL; sel->remaining = k; }
}

__global__ void rs_hist(const ull* __restrict__ keys, int n, const Sel* __restrict__ sel,
                        int shift, int pass, int* __restrict__ hist) {
  __shared__ int lh[256];
  lh[threadIdx.x] = 0;
  __syncthreads();
  int i = blockIdx.x * 256 + threadIdx.x;
  if (i < n) {
    ull k = keys[i];
    bool ok = (pass == 0) || (((k ^ sel->prefix) >> (shift + 8)) == 0);
    if (ok) atomicAdd(&lh[(int)((k >> shift) & 255)], 1);
  }
  __syncthreads();
  if (lh[threadIdx.x]) atomicAdd(&hist[threadIdx.x], lh[threadIdx.x]);
}

__global__ void rs_pick(const int* __restrict__ hist, Sel* sel, int shift) {
  __shared__ int lh[256];
  lh[threadIdx.x] = hist[threadIdx.x];
  __syncthreads();
  if (threadIdx.x == 0) {
    int rem = sel->remaining;
    for (int b = 255; b >= 0; --b) {
      int c = lh[b];
      if (c >= rem) { sel->prefix |= ((ull)b) << shift; break; }
      rem -= c;
    }
    sel->remaining = rem;
  }
}

__global__ void eq_flags(const ull* __restrict__ keys, const Sel* __restrict__ sel,
                         int* __restrict__ eqf, int n) {
  int i = blockIdx.x * 256 + threadIdx.x;
  if (i < n) eqf[i] = (keys[i] == sel->prefix) ? 1 : 0;
}

__global__ void kept_flags(const ull* __restrict__ keys, const Sel* __restrict__ sel,
                           const int* __restrict__ eqpre, int* __restrict__ kept, int n) {
  int i = blockIdx.x * 256 + threadIdx.x;
  if (i < n) {
    ull u = keys[i], p = sel->prefix;
    kept[i] = (u > p || (u == p && eqpre[i] < sel->remaining)) ? 1 : 0;
  }
}

// knid = new id if kept else -1; idx[newid] = old id.
__global__ void build_idx(const int* __restrict__ kept, const int* __restrict__ npre,
                          int* __restrict__ knid, int* __restrict__ idx, int n) {
  int i = blockIdx.x * 256 + threadIdx.x;
  if (i < n) {
    if (kept[i]) {
      int nid = npre[i];
      knid[i] = nid;
      idx[nid] = i;
    } else {
      knid[i] = -1;
    }
  }
}

__global__ void gather_rows(const double* __restrict__ xs, const int* __restrict__ idx,
                            double* __restrict__ xo, int k) {
  int i = blockIdx.x * 256 + threadIdx.x;
  if (i < k * 128) xo[i] = xs[(size_t)idx[i >> 7] * 128 + (i & 127)];
}

__global__ void scatter_add_rows(float* __restrict__ h, const float* __restrict__ t,
                                 const int* __restrict__ idx, int k) {
  int i = blockIdx.x * 256 + threadIdx.x;
  if (i < k * 128) h[(size_t)idx[i >> 7] * 128 + (i & 127)] += t[i];
}

// ---------------- host ----------------

extern "C" void kernel_launch(void* const* d_in, const int* in_sizes, int n_in,
                              void* d_out, int out_size, void* d_ws, size_t ws_size,
                              hipStream_t stream) {
  (void)in_sizes; (void)out_size;
  if (n_in < 17) return;
  const float* x_in   = (const float*)d_in[0];
  const int*   ei     = (const int*)  d_in[1];
  const float* in_W   = (const float*)d_in[2];
  const float* in_b   = (const float*)d_in[3];
  const float* dn_W   = (const float*)d_in[4];
  const float* dn_b   = (const float*)d_in[5];
  const float* dn_g   = (const float*)d_in[6];
  const float* dn_bt  = (const float*)d_in[7];
  const float* pool_w = (const float*)d_in[8];
  const float* bot_W  = (const float*)d_in[9];
  const float* bot_b  = (const float*)d_in[10];
  const float* up_W   = (const float*)d_in[11];
  const float* up_b   = (const float*)d_in[12];
  const float* up_g   = (const float*)d_in[13];
  const float* up_bt  = (const float*)d_in[14];
  const float* out_W  = (const float*)d_in[15];
  const float* out_b  = (const float*)d_in[16];
  float* outp = (float*)d_out;

  char* base = (char*)d_ws;
  size_t off = 0;
  auto alloc = [&](size_t b) -> void* {
    void* r = base + off;
    off = (off + b + 255) & ~(size_t)255;
    return r;
  };
  // Two big fp64 ping-pong buffers (102.4 MB each); fp32 skip snapshots alias
  // their dead regions per the liveness schedule below.
  double* bufA = (double*)alloc((size_t)N0_ * 128 * 8);
  double* bufB = (double*)alloc((size_t)N0_ * 128 * 8);
  float* xs0f = (float*)((char*)bufB + HALF_BYTES);   // 51.2 MB  (B upper half)
  float* xs1f = (float*)((char*)bufA + HALF_BYTES);   // 25.6 MB  (A[51.2,76.8))
  float* xs2f = (float*)((char*)bufA + HALF_BYTES + 25600000ULL); // 12.8 MB

  int* csrs0 = (int*)alloc((size_t)EDG * 4);
  int* csrs1 = (int*)alloc((size_t)CAP1 * 4);
  int* csrs2 = (int*)alloc((size_t)CAP2 * 4);
  int* csrs3 = (int*)alloc((size_t)CAP3 * 4);
  double* csrw0 = (double*)alloc((size_t)EDG * 8);
  double* csrw1 = (double*)alloc((size_t)CAP1 * 8);
  double* csrw2 = (double*)alloc((size_t)CAP2 * 8);
  double* csrw3 = (double*)alloc((size_t)CAP3 * 8);
  int* csro0 = (int*)alloc((size_t)(N0_ + 1) * 4);
  int* csro1 = (int*)alloc((size_t)(N1_ + 1) * 4);
  int* csro2 = (int*)alloc((size_t)(N2_ + 1) * 4);
  int* csro3 = (int*)alloc((size_t)(N3_ + 1) * 4);
  double* dinv0 = (double*)alloc((size_t)N0_ * 8); double* dgi0 = (double*)alloc((size_t)N0_ * 8);
  double* dinv1 = (double*)alloc((size_t)N1_ * 8); double* dgi1 = (double*)alloc((size_t)N1_ * 8);
  double* dinv2 = (double*)alloc((size_t)N2_ * 8); double* dgi2 = (double*)alloc((size_t)N2_ * 8);
  double* dinv3 = (double*)alloc((size_t)N3_ * 8); double* dgi3 = (double*)alloc((size_t)N3_ * 8);
  ull* keys = (ull*)alloc((size_t)N0_ * 8);
  int* eqf   = (int*)alloc((size_t)N0_ * 4);
  int* eqpre = (int*)alloc((size_t)(N0_ + 1) * 4);
  int* kept  = (int*)alloc((size_t)N0_ * 4);
  int* npre  = (int*)alloc((size_t)(N0_ + 1) * 4);
  int* knid  = (int*)alloc((size_t)N0_ * 4);
  int* degcnt = (int*)alloc((size_t)N0_ * 4);
  int* cursor = (int*)alloc((size_t)N0_ * 4);
  int* idx0 = (int*)alloc((size_t)N1_ * 4);
  int* idx1 = (int*)alloc((size_t)N2_ * 4);
  int* idx2 = (int*)alloc((size_t)N3_ * 4);
  int* hist = (int*)alloc(8 * 256 * 4);
  Sel* sel  = (Sel*)alloc(256);
  double* bns = (double*)alloc((size_t)256 * 256 * 8);  // per-block BN partials
  double* ssb = (double*)alloc(256 * 8);
  double* wn  = (double*)alloc(256);
  if (off > ws_size) {  // signal: absmax will be ~ws_size
    sentinel_k<<<1, 64, 0, stream>>>(outp, (float)ws_size);
    return;
  }

  const int nL[4]   = {N0_, N1_, N2_, N3_};
  int* csrsL[4] = {csrs0, csrs1, csrs2, csrs3};
  double* csrwL[4] = {csrw0, csrw1, csrw2, csrw3};
  int* csroL[4] = {csro0, csro1, csro2, csro3};
  double* dinvL[4] = {dinv0, dinv1, dinv2, dinv3};
  double* dgiL[4]  = {dgi0, dgi1, dgi2, dgi3};
  int* idxL[3] = {idx0, idx1, idx2};

  auto cdiv = [](int a, int b) { return (a + b - 1) / b; };

  auto bn_d = [&](double* xp, int n, const float* g, const float* b, float* snap) {
    bn_stats<double><<<256, 256, 0, stream>>>(xp, n, bns);
    bn_final<<<1, 128, 0, stream>>>(bns, g, b, 1.0 / (double)n, ssb);
    bn_apply_relu<double><<<cdiv(n * 128, 256), 256, 0, stream>>>(xp, ssb, snap,
                                                                  (size_t)n * 128);
  };
  auto bn_f = [&](float* xp, int n, const float* g, const float* b) {
    bn_stats<float><<<256, 256, 0, stream>>>(xp, n, bns);
    bn_final<<<1, 128, 0, stream>>>(bns, g, b, 1.0 / (double)n, ssb);
    bn_apply_relu<float><<<cdiv(n * 128, 256), 256, 0, stream>>>(xp, ssb, nullptr,
                                                                 (size_t)n * 128);
  };

  // pool level i: top-k on xcur; gather kept rows into xnext; build level i+1
  // CSR directly from level-i CSR (no edge list, no atomics).
  auto pool = [&](int i, const double* xcur, double* xnext) {
    int n = nL[i], k = nL[i + 1];
    wnorm_k<<<1, 128, 0, stream>>>(pool_w + i * 128, wn);
    score_key_k<<<cdiv(n, 2), 256, 0, stream>>>(xcur, pool_w + i * 128, wn, keys, n);
    sel_init<<<1, 64, 0, stream>>>(sel, k);
    hipMemsetAsync(hist, 0, 8 * 256 * 4, stream);
    for (int p = 0; p < 8; ++p) {
      int shift = 56 - 8 * p;
      rs_hist<<<cdiv(n, 256), 256, 0, stream>>>(keys, n, sel, shift, p, hist + p * 256);
      rs_pick<<<1, 256, 0, stream>>>(hist + p * 256, sel, shift);
    }
    eq_flags<<<cdiv(n, 256), 256, 0, stream>>>(keys, sel, eqf, n);
    scan_excl<<<1, 1024, 0, stream>>>(eqf, eqpre, n);
    kept_flags<<<cdiv(n, 256), 256, 0, stream>>>(keys, sel, eqpre, kept, n);
    scan_excl<<<1, 1024, 0, stream>>>(kept, npre, n);
    build_idx<<<cdiv(n, 256), 256, 0, stream>>>(kept, npre, knid, idxL[i], n);
    gather_rows<<<cdiv(k * 128, 256), 256, 0, stream>>>(xcur, idxL[i], xnext, k);
    // next-level CSR: deg -> dinv/dgi -> offsets -> fill
    next_deg<<<cdiv(n, 256), 256, 0, stream>>>(csroL[i], csrsL[i], knid, degcnt, n);
    fin_deg<<<cdiv(k, 256), 256, 0, stream>>>(degcnt, dinvL[i + 1], dgiL[i + 1], k);
    scan_excl<<<1, 1024, 0, stream>>>(degcnt, csroL[i + 1], k);
    next_fill<<<cdiv(n, 256), 256, 0, stream>>>(csroL[i], csrsL[i], knid,
        csroL[i + 1], dinvL[i + 1], csrsL[i + 1], csrwL[i + 1], n);
  };

  // ---- level 0 CSR (from raw edge list) ----
  hipMemsetAsync(degcnt, 0, (size_t)N0_ * 4, stream);
  count_deg<<<cdiv(EDG, 256), 256, 0, stream>>>(ei + EDG, EDG, degcnt);
  fin_deg<<<cdiv(N0_, 256), 256, 0, stream>>>(degcnt, dinv0, dgi0, N0_);
  scan_excl<<<1, 1024, 0, stream>>>(degcnt, csro0, N0_);
  hipMemsetAsync(cursor, 0, (size_t)N0_ * 4, stream);
  csr_fill<<<cdiv(EDG, 256), 256, 0, stream>>>(ei, ei + EDG, EDG, csro0, cursor,
                                               csrs0, csrw0, dinv0);

  // ---- initial conv (agg-first: agg(x W)+b = (agg x) W + b) ----
  agg_conv<float, double, false><<<cdiv(N0_, 2), 256, 0, stream>>>(
      x_in, csro0, csrs0, csrw0, dinv0, dgi0, nullptr, bufB, N0_);
  matmul128<double, double, double><<<cdiv(N0_, 64), 256, 0, stream>>>(bufB, in_W, in_b, bufA, N0_);

  // ---- down level 0: x in A, h in B, y back to A; xs0f -> B upper; x1 -> B lower ----
  matmul128<double, double, double><<<cdiv(N0_, 64), 256, 0, stream>>>(bufA, dn_W, nullptr, bufB, N0_);
  agg_conv<double, double, false><<<cdiv(N0_, 2), 256, 0, stream>>>(
      bufB, csro0, csrs0, csrw0, dinv0, dgi0, dn_b, bufA, N0_);
  bn_d(bufA, N0_, dn_g, dn_bt, xs0f);
  pool(0, bufA, bufB);

  // ---- down level 1: x in B lower, h in A lower, y back to B; xs1f -> A+51.2M ----
  matmul128<double, double, double><<<cdiv(N1_, 64), 256, 0, stream>>>(bufB, dn_W + 16384, nullptr, bufA, N1_);
  agg_conv<double, double, false><<<cdiv(N1_, 2), 256, 0, stream>>>(
      bufA, csro1, csrs1, csrw1, dinv1, dgi1, dn_b + 128, bufB, N1_);
  bn_d(bufB, N1_, dn_g + 128, dn_bt + 128, xs1f);
  pool(1, bufB, bufA);

  // ---- down level 2: x in A lower, h in B lower, y back to A; xs2f -> A+76.8M ----
  matmul128<double, double, double><<<cdiv(N2_, 64), 256, 0, stream>>>(bufA, dn_W + 32768, nullptr, bufB, N2_);
  agg_conv<double, double, false><<<cdiv(N2_, 2), 256, 0, stream>>>(
      bufB, csro2, csrs2, csrw2, dinv2, dgi2, dn_b + 256, bufA, N2_);
  bn_d(bufA, N2_, dn_g + 256, dn_bt + 256, xs2f);
  pool(2, bufA, bufB);

  // ---- bottom: x3 in B lower, h3 -> A lower, z3 (fp32, relu) -> B lower ----
  matmul128<double, double, double><<<cdiv(N3_, 64), 256, 0, stream>>>(bufB, bot_W, nullptr, bufA, N3_);
  float* zf = (float*)bufB;
  float* hf = (float*)bufA;
  float* tf = outp;  // d_out as scratch until final write (fully overwritten)
  agg_conv<double, float, true><<<cdiv(N3_, 2), 256, 0, stream>>>(
      bufA, csro3, csrs3, csrw3, dinv3, dgi3, bot_b, zf, N3_);

  // ---- up path (fp32 data + fp32 accumulate): z in B lower, hf in A lower ----
  for (int u = 0; u < 3; ++u) {
    int l = 2 - u;
    int nl = nL[l], nz = nL[l + 1];
    const float* Wt = up_W + u * 32768;          // rows [0:128)  -> unpooled part
    const float* Wb = up_W + u * 32768 + 16384;  // rows [128:256)-> skip part
    const float* xsf = (u == 0) ? xs2f : (u == 1) ? xs1f : xs0f;
    matmul128<float, float, float><<<cdiv(nz, 64), 256, 0, stream>>>(zf, Wt, nullptr, tf, nz);
    matmul128<float, float, float><<<cdiv(nl, 64), 256, 0, stream>>>(xsf, Wb, nullptr, hf, nl);
    scatter_add_rows<<<cdiv(nz * 128, 256), 256, 0, stream>>>(hf, tf, idxL[l], nz);
    agg_conv<float, float, false><<<cdiv(nl, 2), 256, 0, stream>>>(
        hf, csroL[l], csrsL[l], csrwL[l], dinvL[l], dgiL[l], up_b + u * 128, zf, nl);
    bn_f(zf, nl, up_g + u * 128, up_bt + u * 128);
  }

  // ---- final conv -> d_out ----
  matmul128<float, float, float><<<cdiv(N0_, 64), 256, 0, stream>>>(zf, out_W, nullptr, hf, N0_);
  agg_conv<float, float, false><<<cdiv(N0_, 2), 256, 0, stream>>>(
      hf, csro0, csrs0, csrw0, dinv0, dgi0, out_b, outp, N0_);
}